// Round 10
// baseline (584.730 us; speedup 1.0000x reference)
//
#include <hip/hip_runtime.h>

// Problem constants (from reference)
#define BQ_B   8
#define BQ_N   4096
#define NS     32
#define C1     32
#define C2     64
#define R2C    0.0625f
#define NPTS   (BQ_B * BQ_N)

// ---- spatial grid ----
#define GD     32                  // cells per dim, cell size 0.25, origin -4 (clamped)
#define NC_B   (GD * GD * GD)      // 32768 cells per batch
#define NCELLS (BQ_B * NC_B)       // 262144 total
#define SCAN_B 1024
#define NBLK2  (NCELLS / SCAN_B)   // 256

__device__ __forceinline__ int cell_coord(float x) {
    int i = (int)floorf((x + 4.0f) * 4.0f);
    return i < 0 ? 0 : (i > GD - 1 ? GD - 1 : i);
}

// ---------- grid build ----------
__global__ __launch_bounds__(256) void grid_count(
    const float* __restrict__ xyz, unsigned* __restrict__ counts,
    unsigned* __restrict__ pcell, unsigned* __restrict__ ppos)
{
    const int i = blockIdx.x * 256 + threadIdx.x;
    const float x = xyz[3 * i], y = xyz[3 * i + 1], z = xyz[3 * i + 2];
    const int ix = cell_coord(x), iy = cell_coord(y), iz = cell_coord(z);
    const unsigned cid = (unsigned)(((i >> 12) * GD + iz) * GD + iy) * GD + ix;
    pcell[i] = cid;
    ppos[i] = atomicAdd(&counts[cid], 1u);
}

// fused: per-block exclusive scan + (last block) top-level scan of blocksums
__global__ __launch_bounds__(1024) void scan1f(
    const unsigned* __restrict__ counts, unsigned* __restrict__ partial,
    unsigned* __restrict__ blocksum, unsigned* __restrict__ blockoff,
    unsigned* __restrict__ done)
{
    __shared__ unsigned wsum[16];
    __shared__ unsigned ws2[4];
    __shared__ unsigned lastv;
    const int tid = threadIdx.x, lane = tid & 63, w = tid >> 6;
    const int g = blockIdx.x * 1024 + tid;
    const unsigned v = counts[g];
    unsigned incl = v;
    #pragma unroll
    for (int d = 1; d < 64; d <<= 1) {
        unsigned t = __shfl_up(incl, d, 64);
        if (lane >= d) incl += t;
    }
    if (lane == 63) wsum[w] = incl;
    __syncthreads();
    if (w == 0 && lane < 16) {
        const unsigned s = wsum[lane];
        unsigned si = s;
        #pragma unroll
        for (int d = 1; d < 16; d <<= 1) {
            unsigned t = __shfl_up(si, d, 64);
            if (lane >= d) si += t;
        }
        wsum[lane] = si - s;
        if (lane == 15) blocksum[blockIdx.x] = si;
    }
    __syncthreads();
    partial[g] = wsum[w] + incl - v;

    // ---- last-block does the 256-entry top-level scan ----
    __threadfence();                       // each thread: make its stores device-visible
    __syncthreads();                       // all threads fenced before the signal
    if (tid == 0) lastv = atomicAdd(done, 1u);   // device-scope
    __syncthreads();
    if (lastv == NBLK2 - 1) {              // block-uniform branch
        __threadfence();                   // acquire side
        unsigned bv = 0, bincl = 0;
        if (tid < NBLK2) {
            bv = blocksum[tid];
            bincl = bv;
            #pragma unroll
            for (int d = 1; d < 64; d <<= 1) {
                unsigned t = __shfl_up(bincl, d, 64);
                if (lane >= d) bincl += t;
            }
            if (lane == 63) ws2[w] = bincl;
        }
        __syncthreads();
        if (tid < NBLK2) {
            unsigned off = 0;
            #pragma unroll
            for (int j = 0; j < 4; ++j) if (j < w) off += ws2[j];
            blockoff[tid] = off + bincl - bv;
        }
    }
}

// fused: cellstart finalize (all 262144 cells) + point scatter (first NPTS threads)
__global__ __launch_bounds__(256) void grid_scatterF(
    const float* __restrict__ xyz,
    const unsigned* __restrict__ partial, const unsigned* __restrict__ blockoff,
    const unsigned* __restrict__ pcell, const unsigned* __restrict__ ppos,
    unsigned* __restrict__ cellstart, float4* __restrict__ pts)
{
    const int g = blockIdx.x * 256 + threadIdx.x;   // 1024 blocks
    cellstart[g] = partial[g] + blockoff[g >> 10];
    if (g == 0) cellstart[NCELLS] = NPTS;
    if (g < NPTS) {
        const unsigned cid = pcell[g];
        const unsigned pos = partial[cid] + blockoff[cid >> 10] + ppos[g];
        float4 v;
        v.x = xyz[3 * g];
        v.y = xyz[3 * g + 1];
        v.z = xyz[3 * g + 2];
        v.w = __uint_as_float((unsigned)(g & (BQ_N - 1)));
        pts[pos] = v;
    }
}

// ---------- main: grid ball-query + atomic-free quarter-split MLP ----------
#define CB  8    // centers per block (grid 4096)
#define CW  2    // centers per wave
#define MCH 64   // MLP chunk samples

__global__ __launch_bounds__(256, 8) void lse_grid6(
    const float* __restrict__ xyz,
    const unsigned* __restrict__ cellstart,
    const float4* __restrict__ pts,
    const float* __restrict__ w1, const float* __restrict__ b1,
    const float* __restrict__ w2, const float* __restrict__ b2,
    float* __restrict__ out)
{
    __shared__ unsigned cand[4][64];          // per-wave candidate src positions
    __shared__ unsigned queue[4][CW * NS];    // compact entries: (pl<<20)|src
    __shared__ int      qlen[4];
    __shared__ float    ctr[CB][3];
    __shared__ unsigned kc[CB];               // k per center
    __shared__ unsigned qsl[CB];              // wave-local queue start of center pl
    __shared__ float    hres[MCH][C2 + 1];    // h2 results: [chunk-sample][o], stride 65

    const int tid  = threadIdx.x, lane = tid & 63, wf = tid >> 6;
    const int p0   = blockIdx.x * CB;         // never straddles a batch
    const int b    = p0 >> 12;

    // hoisted wave-uniform center coords (scalar loads)
    float scx[CW], scy[CW], scz[CW];
    #pragma unroll
    for (int jc = 0; jc < CW; ++jc) {
        const int g = __builtin_amdgcn_readfirstlane(p0 + wf * CW + jc);
        float x = xyz[3 * g], y = xyz[3 * g + 1], z = xyz[3 * g + 2];
        scx[jc] = __int_as_float(__builtin_amdgcn_readfirstlane(__float_as_int(x)));
        scy[jc] = __int_as_float(__builtin_amdgcn_readfirstlane(__float_as_int(y)));
        scz[jc] = __int_as_float(__builtin_amdgcn_readfirstlane(__float_as_int(z)));
    }
    if (lane == 0) {
        #pragma unroll
        for (int jc = 0; jc < CW; ++jc) {
            ctr[wf * CW + jc][0] = scx[jc];
            ctr[wf * CW + jc][1] = scy[jc];
            ctr[wf * CW + jc][2] = scz[jc];
        }
    }

    int myqlen = 0;
    #pragma unroll
    for (int jc = 0; jc < CW; ++jc) {
        const int pl = wf * CW + jc;
        const float cx = scx[jc], cy = scy[jc], cz = scz[jc];
        const int icx = __builtin_amdgcn_readfirstlane(cell_coord(cx));
        const int icy = __builtin_amdgcn_readfirstlane(cell_coord(cy));
        const int icz = __builtin_amdgcn_readfirstlane(cell_coord(cz));
        const int lo = icx > 0 ? icx - 1 : 0;
        const int hi = icx < GD - 1 ? icx + 1 : GD - 1;

        // 9 candidate ranges from wave-uniform scalar loads
        unsigned st[9], cn[9], of[9];
        unsigned T = 0;
        #pragma unroll
        for (int r = 0; r < 9; ++r) {
            const int dz = r / 3 - 1, dy = r % 3 - 1;
            const int rz = icz + dz, ry = icy + dy;
            const bool ok = (rz >= 0) & (rz < GD) & (ry >= 0) & (ry < GD);
            const int rzc = rz < 0 ? 0 : (rz > GD - 1 ? GD - 1 : rz);
            const int ryc = ry < 0 ? 0 : (ry > GD - 1 ? GD - 1 : ry);
            const int cbase = ((b * GD + rzc) * GD + ryc) * GD;
            const unsigned s = cellstart[cbase + lo];
            const unsigned e = cellstart[cbase + hi + 1];
            st[r] = s;
            cn[r] = ok ? e - s : 0u;
            of[r] = T;
            T += cn[r];
        }

        int kcur = 0;
        for (unsigned tb = 0; tb < T; tb += 64) {
            const unsigned t = tb + (unsigned)lane;
            unsigned src = 0;
            #pragma unroll
            for (int r = 0; r < 9; ++r) {          // SGPR operands, pure VALU
                const unsigned d = t - of[r];
                if (d < cn[r]) src = st[r] + d;
            }
            const bool inb = t < T;
            const float4 q4 = pts[src];            // one dwordx4 gather
            const float dx = q4.x - cx, dy = q4.y - cy, dz = q4.z - cz;
            const float d2 = fmaf(dz, dz, fmaf(dy, dy, dx * dx));
            const bool nearb  = inb && (d2 < R2C + 1e-5f);
            const bool strict = inb && (d2 < R2C - 1e-5f);
            bool valid = strict;
            if (nearb && !strict) {                // rare: exact fp64 adjudication
                const double ddx = (double)q4.x - (double)cx;
                const double ddy = (double)q4.y - (double)cy;
                const double ddz = (double)q4.z - (double)cz;
                valid = (ddx * ddx + ddy * ddy + ddz * ddz) < 0.0625;
            }
            const unsigned long long mask = __ballot(valid);
            if (mask) {
                const unsigned mlo = (unsigned)mask, mhi = (unsigned)(mask >> 32);
                const int rank = __builtin_amdgcn_mbcnt_hi(
                                     mhi, __builtin_amdgcn_mbcnt_lo(mlo, 0));
                const int pos = kcur + rank;
                if (valid && pos < 64) cand[wf][pos] = src;  // P(ktot>64) negligible
                kcur += __popcll(mask);
            }
        }

        const int k = kcur < NS ? kcur : NS;       // == unique_cnt
        if (lane == 0) { kc[pl] = (unsigned)k; qsl[pl] = (unsigned)myqlen; }

        int slot = lane;
        if (kcur > NS) {                           // rare: pick 32 smallest idx
            unsigned key = 0x7FFFFFFFu;
            if (lane < kcur && lane < 64) {
                const unsigned qi = __float_as_uint(pts[cand[wf][lane]].w);
                key = (qi << 6) | (unsigned)lane;
            }
            #pragma unroll
            for (int size = 2; size <= 64; size <<= 1) {
                #pragma unroll
                for (int stride = size >> 1; stride > 0; stride >>= 1) {
                    const unsigned partner = (unsigned)__shfl_xor((int)key, stride, 64);
                    const bool keepmin = ((lane & stride) == 0) == ((lane & size) == 0);
                    key = keepmin ? (key < partner ? key : partner)
                                  : (key > partner ? key : partner);
                }
            }
            slot = (int)(key & 63u);
        }
        if (lane < k)
            queue[wf][myqlen + lane] = ((unsigned)pl << 20) | cand[wf][slot];
        myqlen += k;
    }
    if (lane == 0) qlen[wf] = myqlen;
    __syncthreads();

    // ---- MLP: wave = output quarter, lane = chunk sample; no atomics ----
    const int q0 = qlen[0], q1 = qlen[1], q2 = qlen[2], q3 = qlen[3];
    const int o1 = q0, o2 = q0 + q1, o3 = o2 + q2;
    const int Qtot = o3 + q3;

    // owners: thread reduces (plA, oA) and (plB, oA); all wave-uniform except oA
    const int plA = tid >> 6;                     // 0..3 (== wf)
    const int oA  = lane;
    const int plB = plA + 4;                      // 4..7
    const int s0A = ((tid & 128) ? o1 : 0)  + (int)qsl[plA];   // plA>>1 in {0,1}
    const int s0B = ((tid & 128) ? o3 : o2) + (int)qsl[plB];   // plB>>1 in {2,3}
    const int kA  = (int)kc[plA];
    const int kB  = (int)kc[plB];
    float mxA = 0.f, mxB = 0.f;                   // relu outputs >= 0

    for (int cb = 0; cb < Qtot; cb += MCH) {
        const int cq = Qtot - cb < MCH ? Qtot - cb : MCH;
        const int s = cb + lane;                  // this lane's sample
        if (lane < cq) {
            int w, loc;
            if (s < o1)      { w = 0; loc = s; }
            else if (s < o2) { w = 1; loc = s - o1; }
            else if (s < o3) { w = 2; loc = s - o2; }
            else             { w = 3; loc = s - o3; }
            const unsigned e = queue[w][loc];
            const int pl = (int)(e >> 20);
            const unsigned src = e & 0xFFFFFu;
            const float4 f4 = pts[src];           // L1/L2-hot gather
            const float rx = f4.x - ctr[pl][0];
            const float ry = f4.y - ctr[pl][1];
            const float rz = f4.z - ctr[pl][2];

            float h1[C1];
            #pragma unroll
            for (int c = 0; c < C1; ++c) {        // w1/b1 uniform -> scalar loads
                float a = fmaf(w1[c * 3 + 2], rz,
                          fmaf(w1[c * 3 + 1], ry,
                          fmaf(w1[c * 3 + 0], rx, b1[c])));
                h1[c] = a > 0.f ? a : 0.f;
            }
            const float* w2q = w2 + (wf << 9);    // rows [wf*16, wf*16+16)
            const float* b2q = b2 + (wf << 4);
            float* hrow = &hres[lane][wf << 4];
            #pragma unroll 4
            for (int i = 0; i < 16; ++i) {        // two independent chains
                float ax = 0.f, ay = 0.f;
                #pragma unroll
                for (int c = 0; c < C1; c += 2) {
                    ax = fmaf(w2q[i * 32 + c],     h1[c],     ax);
                    ay = fmaf(w2q[i * 32 + c + 1], h1[c + 1], ay);
                }
                float acc = ax + ay + b2q[i];
                hrow[i] = acc > 0.f ? acc : 0.f;  // plain store, unique writer
            }
        }
        __syncthreads();
        // reduction: wave-uniform segments clipped to this chunk
        {
            int sl = s0A > cb ? s0A : cb;
            int sh = s0A + kA < cb + cq ? s0A + kA : cb + cq;
            for (int s2 = sl; s2 < sh; ++s2) mxA = fmaxf(mxA, hres[s2 - cb][oA]);
            sl = s0B > cb ? s0B : cb;
            sh = s0B + kB < cb + cq ? s0B + kB : cb + cq;
            for (int s2 = sl; s2 < sh; ++s2) mxB = fmaxf(mxB, hres[s2 - cb][oA]);
        }
        __syncthreads();                          // hres reused next chunk
    }

    // ---- write out: coalesced 64-wide rows + density ----
    out[(size_t)(p0 + plA) * (C2 + 1) + oA] = mxA;
    out[(size_t)(p0 + plB) * (C2 + 1) + oA] = mxB;
    if (tid < CB)
        out[(size_t)(p0 + tid) * (C2 + 1) + C2] = (float)kc[tid] * (1.0f / (float)C2);
}

// ================= fallback: R4 brute-force kernel (ws too small) =================
#define PBLK   16
#define CPW    4
#define BAND   2e-4f

__global__ __launch_bounds__(256, 8) void lse_fallback(
    const float* __restrict__ xyz,
    const float* __restrict__ w1, const float* __restrict__ b1,
    const float* __restrict__ w2, const float* __restrict__ b2,
    float* __restrict__ out)
{
    __shared__ int      lists[PBLK][NS];
    __shared__ int      counts[PBLK];
    __shared__ int      queue[PBLK * NS];
    __shared__ unsigned pooled[PBLK][C2 + 1];
    __shared__ float    ctr[PBLK][3];
    __shared__ float    dens[PBLK];
    __shared__ int      qtotal;

    const int tid = threadIdx.x, lane = tid & 63, wf = tid >> 6;
    const int pt0 = blockIdx.x * PBLK;
    const int bbase = (pt0 >> 12) << 12;

    for (int u = tid; u < PBLK * (C2 + 1); u += 256) ((unsigned*)pooled)[u] = 0u;
    if (tid < PBLK) {
        ctr[tid][0] = xyz[(size_t)(pt0 + tid) * 3 + 0];
        ctr[tid][1] = xyz[(size_t)(pt0 + tid) * 3 + 1];
        ctr[tid][2] = xyz[(size_t)(pt0 + tid) * 3 + 2];
    }
    const int c0 = pt0 + wf * CPW;
    float c2x[CPW], c2y[CPW], c2z[CPW], scc[CPW];
    #pragma unroll
    for (int j = 0; j < CPW; ++j) {
        const int g = __builtin_amdgcn_readfirstlane(c0 + j);
        const float cx = xyz[(size_t)g * 3 + 0];
        const float cy = xyz[(size_t)g * 3 + 1];
        const float cz = xyz[(size_t)g * 3 + 2];
        c2x[j] = -2.0f * cx; c2y[j] = -2.0f * cy; c2z[j] = -2.0f * cz;
        scc[j] = fmaf(cx, cx, fmaf(cy, cy, cz * cz)) - (R2C + BAND);
    }
    int cnt[CPW];
    #pragma unroll
    for (int j = 0; j < CPW; ++j) cnt[j] = 0;

    const float* xb = xyz + (size_t)bbase * 3;
    float qx = xb[lane * 3 + 0], qy = xb[lane * 3 + 1], qz = xb[lane * 3 + 2];
    for (int m0 = 0; m0 < BQ_N; m0 += 64) {
        float nqx = 0.f, nqy = 0.f, nqz = 0.f;
        if (m0 + 64 < BQ_N) {
            const int mn = m0 + 64 + lane;
            nqx = xb[mn * 3 + 0]; nqy = xb[mn * 3 + 1]; nqz = xb[mn * 3 + 2];
        }
        const float nsq = -fmaf(qx, qx, fmaf(qy, qy, qz * qz));
        float t[CPW]; unsigned long long msk[CPW];
        #pragma unroll
        for (int j = 0; j < CPW; ++j) {
            t[j] = fmaf(qx, c2x[j], fmaf(qy, c2y[j], fmaf(qz, c2z[j], scc[j])));
            msk[j] = __ballot(t[j] < nsq);
        }
        if ((msk[0] | msk[1] | msk[2] | msk[3]) != 0ull) {
            #pragma unroll
            for (int j = 0; j < CPW; ++j) {
                unsigned long long mask = msk[j];
                if (mask == 0ull) continue;
                const float u = t[j] - nsq;
                const bool nearb = (mask >> lane) & 1ull;
                const bool strict = u < (-2.0f * BAND);
                bool valid = strict;
                const unsigned long long mS = __ballot(strict);
                if (mS != mask) {
                    if (nearb && !strict) {
                        const double cx = -0.5 * (double)c2x[j];
                        const double cy = -0.5 * (double)c2y[j];
                        const double cz = -0.5 * (double)c2z[j];
                        const double dx = (double)qx - cx;
                        const double dy = (double)qy - cy;
                        const double dz = (double)qz - cz;
                        valid = (dx * dx + dy * dy + dz * dz) < 0.0625;
                    }
                    mask = __ballot(valid);
                    if (mask == 0ull) continue;
                }
                const unsigned mlo = (unsigned)mask, mhi = (unsigned)(mask >> 32);
                const int rank = __builtin_amdgcn_mbcnt_hi(
                                     mhi, __builtin_amdgcn_mbcnt_lo(mlo, 0));
                const int pos = cnt[j] + rank;
                if (valid && pos < NS) lists[wf * CPW + j][pos] = m0 + lane;
                cnt[j] += __popcll(mask);
            }
        }
        qx = nqx; qy = nqy; qz = nqz;
    }
    if (lane == 0) {
        #pragma unroll
        for (int j = 0; j < CPW; ++j) counts[wf * CPW + j] = cnt[j];
    }
    __syncthreads();
    if (tid < PBLK) {
        const int p = tid;
        const int ktot = counts[p];
        const int k = ktot < NS ? ktot : NS;
        dens[p] = (float)k * (1.0f / (float)C2);
        int incl = k;
        #pragma unroll
        for (int d = 1; d < PBLK; d <<= 1) {
            int v = __shfl_up(incl, d, 64);
            if (lane >= d) incl += v;
        }
        const int excl = incl - k;
        if (p == PBLK - 1) qtotal = incl;
        for (int j = 0; j < k; ++j) queue[excl + j] = (p << 12) | lists[p][j];
    }
    __syncthreads();
    const int Q = qtotal;
    for (int j = tid; j < Q; j += 256) {
        const int e = queue[j];
        const int p = e >> 12;
        const int idx = e & (BQ_N - 1);
        const float* nb = xyz + (size_t)(bbase + idx) * 3;
        const float rx = nb[0] - ctr[p][0];
        const float ry = nb[1] - ctr[p][1];
        const float rz = nb[2] - ctr[p][2];
        float h1[C1];
        #pragma unroll
        for (int cc = 0; cc < C1; ++cc) {
            float a = fmaf(w1[cc * 3 + 2], rz,
                      fmaf(w1[cc * 3 + 1], ry,
                      fmaf(w1[cc * 3 + 0], rx, b1[cc])));
            h1[cc] = a > 0.f ? a : 0.f;
        }
        #pragma unroll 2
        for (int o = 0; o < C2; ++o) {
            float acc = b2[o];
            #pragma unroll
            for (int i = 0; i < C1; ++i) acc = fmaf(w2[o * C1 + i], h1[i], acc);
            acc = acc > 0.f ? acc : 0.f;
            atomicMax(&pooled[p][o], __float_as_uint(acc));
        }
    }
    __syncthreads();
    for (int u = tid; u < PBLK * (C2 + 1); u += 256) {
        const int p = u / (C2 + 1);
        const int cc = u % (C2 + 1);
        const float v = (cc < C2) ? __uint_as_float(pooled[p][cc]) : dens[p];
        out[(size_t)(pt0 + p) * (C2 + 1) + cc] = v;
    }
}

extern "C" void kernel_launch(void* const* d_in, const int* in_sizes, int n_in,
                              void* d_out, int out_size, void* d_ws, size_t ws_size,
                              hipStream_t stream) {
    const float* xyz = (const float*)d_in[0];
    const float* w1  = (const float*)d_in[1];
    const float* b1  = (const float*)d_in[2];
    const float* w2  = (const float*)d_in[3];
    const float* b2  = (const float*)d_in[4];
    float* out = (float*)d_out;

    // workspace layout (u32 units):
    // done[4] | counts[NCELLS] | partial[NCELLS] | cellstart[NCELLS+16] |
    // blocksum[256] | blockoff[256] | pcell[NPTS] | ppos[NPTS] | pts[4*NPTS]
    const size_t need = (size_t)(4 + 3 * NCELLS + 16 + 512 + 2 * NPTS + 4 * NPTS) * 4;

    if (ws_size >= need) {
        unsigned* wsu       = (unsigned*)d_ws;
        unsigned* done      = wsu;                      // 4 (only [0] used)
        unsigned* counts    = done + 4;                 // NCELLS
        unsigned* partial   = counts + NCELLS;          // NCELLS
        unsigned* cellstart = partial + NCELLS;         // NCELLS + 16 (sentinel)
        unsigned* blocksum  = cellstart + NCELLS + 16;  // 256
        unsigned* blockoff  = blocksum + 256;           // 256
        unsigned* pcell     = blockoff + 256;           // NPTS
        unsigned* ppos      = pcell + NPTS;             // NPTS
        float4*   pts       = (float4*)(ppos + NPTS);   // NPTS * 4 dwords (16B-aligned)

        hipMemsetAsync(done, 0, (size_t)(4 + NCELLS) * 4, stream);  // done + counts
        grid_count<<<NPTS / 256, 256, 0, stream>>>(xyz, counts, pcell, ppos);
        scan1f<<<NBLK2, SCAN_B, 0, stream>>>(counts, partial, blocksum, blockoff, done);
        grid_scatterF<<<NCELLS / 256, 256, 0, stream>>>(xyz, partial, blockoff,
                                                        pcell, ppos, cellstart, pts);
        lse_grid6<<<NPTS / CB, 256, 0, stream>>>(xyz, cellstart, pts,
                                                 w1, b1, w2, b2, out);
    } else {
        lse_fallback<<<NPTS / PBLK, 256, 0, stream>>>(xyz, w1, b1, w2, b2, out);
    }
}

// Round 11
// 425.229 us; speedup vs baseline: 1.3751x; 1.3751x over previous
//
#include <hip/hip_runtime.h>

// Problem constants (from reference)
#define BQ_B   8
#define BQ_N   4096
#define NS     32
#define C1     32
#define C2     64
#define R2C    0.0625f
#define NPTS   (BQ_B * BQ_N)

// ---- spatial grid ----
#define GD     32                  // cells per dim, cell size 0.25, origin -4 (clamped)
#define NC_B   (GD * GD * GD)      // 32768 cells per batch
#define NCELLS (BQ_B * NC_B)       // 262144 total
#define SCAN_B 1024
#define NBLK2  (NCELLS / SCAN_B)   // 256

__device__ __forceinline__ int cell_coord(float x) {
    int i = (int)floorf((x + 4.0f) * 4.0f);
    return i < 0 ? 0 : (i > GD - 1 ? GD - 1 : i);
}

// ---------- grid build ----------
__global__ __launch_bounds__(256) void grid_count(
    const float* __restrict__ xyz, unsigned* __restrict__ counts,
    unsigned* __restrict__ pcell, unsigned* __restrict__ ppos)
{
    const int i = blockIdx.x * 256 + threadIdx.x;
    const float x = xyz[3 * i], y = xyz[3 * i + 1], z = xyz[3 * i + 2];
    const int ix = cell_coord(x), iy = cell_coord(y), iz = cell_coord(z);
    const unsigned cid = (unsigned)(((i >> 12) * GD + iz) * GD + iy) * GD + ix;
    pcell[i] = cid;
    ppos[i] = atomicAdd(&counts[cid], 1u);
}

// fused: per-block exclusive scan + (last block) top-level scan of blocksums
__global__ __launch_bounds__(1024) void scan1f(
    const unsigned* __restrict__ counts, unsigned* __restrict__ partial,
    unsigned* __restrict__ blocksum, unsigned* __restrict__ blockoff,
    unsigned* __restrict__ done)
{
    __shared__ unsigned wsum[16];
    __shared__ unsigned ws2[4];
    __shared__ unsigned lastv;
    const int tid = threadIdx.x, lane = tid & 63, w = tid >> 6;
    const int g = blockIdx.x * 1024 + tid;
    const unsigned v = counts[g];
    unsigned incl = v;
    #pragma unroll
    for (int d = 1; d < 64; d <<= 1) {
        unsigned t = __shfl_up(incl, d, 64);
        if (lane >= d) incl += t;
    }
    if (lane == 63) wsum[w] = incl;
    __syncthreads();
    if (w == 0 && lane < 16) {
        const unsigned s = wsum[lane];
        unsigned si = s;
        #pragma unroll
        for (int d = 1; d < 16; d <<= 1) {
            unsigned t = __shfl_up(si, d, 64);
            if (lane >= d) si += t;
        }
        wsum[lane] = si - s;
        if (lane == 15) blocksum[blockIdx.x] = si;
    }
    __syncthreads();
    partial[g] = wsum[w] + incl - v;

    // ---- last-block does the 256-entry top-level scan ----
    __threadfence();
    __syncthreads();
    if (tid == 0) lastv = atomicAdd(done, 1u);   // device-scope
    __syncthreads();
    if (lastv == NBLK2 - 1) {              // block-uniform branch
        __threadfence();                   // acquire side
        unsigned bv = 0, bincl = 0;
        if (tid < NBLK2) {
            bv = blocksum[tid];
            bincl = bv;
            #pragma unroll
            for (int d = 1; d < 64; d <<= 1) {
                unsigned t = __shfl_up(bincl, d, 64);
                if (lane >= d) bincl += t;
            }
            if (lane == 63) ws2[w] = bincl;
        }
        __syncthreads();
        if (tid < NBLK2) {
            unsigned off = 0;
            #pragma unroll
            for (int j = 0; j < 4; ++j) if (j < w) off += ws2[j];
            blockoff[tid] = off + bincl - bv;
        }
    }
}

// fused: cellstart finalize (all 262144 cells) + point scatter (first NPTS threads)
__global__ __launch_bounds__(256) void grid_scatterF(
    const float* __restrict__ xyz,
    const unsigned* __restrict__ partial, const unsigned* __restrict__ blockoff,
    const unsigned* __restrict__ pcell, const unsigned* __restrict__ ppos,
    unsigned* __restrict__ cellstart, float4* __restrict__ pts)
{
    const int g = blockIdx.x * 256 + threadIdx.x;   // 1024 blocks
    cellstart[g] = partial[g] + blockoff[g >> 10];
    if (g == 0) cellstart[NCELLS] = NPTS;
    if (g < NPTS) {
        const unsigned cid = pcell[g];
        const unsigned pos = partial[cid] + blockoff[cid >> 10] + ppos[g];
        float4 v;
        v.x = xyz[3 * g];
        v.y = xyz[3 * g + 1];
        v.z = xyz[3 * g + 2];
        v.w = __uint_as_float((unsigned)(g & (BQ_N - 1)));
        pts[pos] = v;
    }
}

// ---------- main: grid ball-query + atomic-free quarter-split MLP ----------
#define CB  8    // centers per block (grid 4096)
#define CW  2    // centers per wave
#define MCH 64   // MLP chunk samples

__global__ __launch_bounds__(256, 8) void lse_grid7(
    const float* __restrict__ xyz,
    const unsigned* __restrict__ cellstart,
    const float4* __restrict__ pts,
    const float* __restrict__ w1, const float* __restrict__ b1,
    const float* __restrict__ w2, const float* __restrict__ b2,
    float* __restrict__ out)
{
    __shared__ unsigned cand[4][64];          // per-wave candidate src positions
    __shared__ unsigned queue[4][CW * NS];    // compact entries: (pl<<20)|src
    __shared__ int      qlen[4];
    __shared__ float    ctr[CB][3];
    __shared__ unsigned kc[CB];               // k per center
    __shared__ unsigned qsl[CB];              // wave-local queue start of center pl
    __shared__ float    hres[MCH][C2 + 1];    // h2 results: [chunk-sample][o], stride 65

    const int tid  = threadIdx.x, lane = tid & 63, wf = tid >> 6;
    const int p0   = blockIdx.x * CB;         // never straddles a batch
    const int b    = p0 >> 12;

    // hoisted wave-uniform center coords (scalar loads)
    float scx[CW], scy[CW], scz[CW];
    #pragma unroll
    for (int jc = 0; jc < CW; ++jc) {
        const int g = __builtin_amdgcn_readfirstlane(p0 + wf * CW + jc);
        float x = xyz[3 * g], y = xyz[3 * g + 1], z = xyz[3 * g + 2];
        scx[jc] = __int_as_float(__builtin_amdgcn_readfirstlane(__float_as_int(x)));
        scy[jc] = __int_as_float(__builtin_amdgcn_readfirstlane(__float_as_int(y)));
        scz[jc] = __int_as_float(__builtin_amdgcn_readfirstlane(__float_as_int(z)));
    }
    if (lane == 0) {
        #pragma unroll
        for (int jc = 0; jc < CW; ++jc) {
            ctr[wf * CW + jc][0] = scx[jc];
            ctr[wf * CW + jc][1] = scy[jc];
            ctr[wf * CW + jc][2] = scz[jc];
        }
    }

    int myqlen = 0;
    #pragma unroll
    for (int jc = 0; jc < CW; ++jc) {
        const int pl = wf * CW + jc;
        const float cx = scx[jc], cy = scy[jc], cz = scz[jc];
        const int icx = __builtin_amdgcn_readfirstlane(cell_coord(cx));
        const int icy = __builtin_amdgcn_readfirstlane(cell_coord(cy));
        const int icz = __builtin_amdgcn_readfirstlane(cell_coord(cz));
        const int lo = icx > 0 ? icx - 1 : 0;
        const int hi = icx < GD - 1 ? icx + 1 : GD - 1;

        // 9 candidate ranges from wave-uniform scalar loads
        unsigned st[9], cn[9], of[9];
        unsigned T = 0;
        #pragma unroll
        for (int r = 0; r < 9; ++r) {
            const int dz = r / 3 - 1, dy = r % 3 - 1;
            const int rz = icz + dz, ry = icy + dy;
            const bool ok = (rz >= 0) & (rz < GD) & (ry >= 0) & (ry < GD);
            const int rzc = rz < 0 ? 0 : (rz > GD - 1 ? GD - 1 : rz);
            const int ryc = ry < 0 ? 0 : (ry > GD - 1 ? GD - 1 : ry);
            const int cbase = ((b * GD + rzc) * GD + ryc) * GD;
            const unsigned s = cellstart[cbase + lo];
            const unsigned e = cellstart[cbase + hi + 1];
            st[r] = s;
            cn[r] = ok ? e - s : 0u;
            of[r] = T;
            T += cn[r];
        }

        int kcur = 0;
        for (unsigned tb = 0; tb < T; tb += 64) {
            const unsigned t = tb + (unsigned)lane;
            unsigned src = 0;
            #pragma unroll
            for (int r = 0; r < 9; ++r) {          // SGPR operands, pure VALU
                const unsigned d = t - of[r];
                if (d < cn[r]) src = st[r] + d;
            }
            const bool inb = t < T;
            const float4 q4 = pts[src];            // one dwordx4 gather
            const float dx = q4.x - cx, dy = q4.y - cy, dz = q4.z - cz;
            const float d2 = fmaf(dz, dz, fmaf(dy, dy, dx * dx));
            const bool nearb  = inb && (d2 < R2C + 1e-5f);
            const bool strict = inb && (d2 < R2C - 1e-5f);
            bool valid = strict;
            if (nearb && !strict) {                // rare: exact fp64 adjudication
                const double ddx = (double)q4.x - (double)cx;
                const double ddy = (double)q4.y - (double)cy;
                const double ddz = (double)q4.z - (double)cz;
                valid = (ddx * ddx + ddy * ddy + ddz * ddz) < 0.0625;
            }
            const unsigned long long mask = __ballot(valid);
            if (mask) {
                const unsigned mlo = (unsigned)mask, mhi = (unsigned)(mask >> 32);
                const int rank = __builtin_amdgcn_mbcnt_hi(
                                     mhi, __builtin_amdgcn_mbcnt_lo(mlo, 0));
                const int pos = kcur + rank;
                if (valid && pos < 64) cand[wf][pos] = src;  // P(ktot>64) negligible
                kcur += __popcll(mask);
            }
        }

        const int k = kcur < NS ? kcur : NS;       // == unique_cnt
        if (lane == 0) { kc[pl] = (unsigned)k; qsl[pl] = (unsigned)myqlen; }

        int slot = lane;
        if (kcur > NS) {                           // rare: pick 32 smallest idx
            unsigned key = 0x7FFFFFFFu;
            if (lane < kcur && lane < 64) {
                const unsigned qi = __float_as_uint(pts[cand[wf][lane]].w);
                key = (qi << 6) | (unsigned)lane;
            }
            #pragma unroll
            for (int size = 2; size <= 64; size <<= 1) {
                #pragma unroll
                for (int stride = size >> 1; stride > 0; stride >>= 1) {
                    const unsigned partner = (unsigned)__shfl_xor((int)key, stride, 64);
                    const bool keepmin = ((lane & stride) == 0) == ((lane & size) == 0);
                    key = keepmin ? (key < partner ? key : partner)
                                  : (key > partner ? key : partner);
                }
            }
            slot = (int)(key & 63u);
        }
        if (lane < k)
            queue[wf][myqlen + lane] = ((unsigned)pl << 20) | cand[wf][slot];
        myqlen += k;
    }
    if (lane == 0) qlen[wf] = myqlen;
    __syncthreads();

    // ---- MLP: wave = output quarter, lane = chunk sample; no atomics ----
    const int q0 = qlen[0], q1 = qlen[1], q2 = qlen[2], q3 = qlen[3];
    const int o1 = q0, o2 = q0 + q1, o3 = o2 + q2;
    const int Qtot = o3 + q3;

    // owners: thread reduces (plA, oA) and (plB, oA)
    const int plA = tid >> 6;                     // 0..3 (== wf)
    const int oA  = lane;
    const int plB = plA + 4;                      // 4..7
    const int s0A = ((tid & 128) ? o1 : 0)  + (int)qsl[plA];
    const int s0B = ((tid & 128) ? o3 : o2) + (int)qsl[plB];
    const int kA  = (int)kc[plA];
    const int kB  = (int)kc[plB];
    float mxA = 0.f, mxB = 0.f;                   // relu outputs >= 0

    for (int cb = 0; cb < Qtot; cb += MCH) {
        const int cq = Qtot - cb < MCH ? Qtot - cb : MCH;
        const int s = cb + lane;                  // this lane's sample
        if (lane < cq) {
            int w, loc;
            if (s < o1)      { w = 0; loc = s; }
            else if (s < o2) { w = 1; loc = s - o1; }
            else if (s < o3) { w = 2; loc = s - o2; }
            else             { w = 3; loc = s - o3; }
            const unsigned e = queue[w][loc];
            const int pl = (int)(e >> 20);
            const unsigned src = e & 0xFFFFFu;
            const float4 f4 = pts[src];           // L1/L2-hot gather
            const float rx = f4.x - ctr[pl][0];
            const float ry = f4.y - ctr[pl][1];
            const float rz = f4.z - ctr[pl][2];

            // c-outer accumulate form: live state = acc[16] (~25 VGPR, no spill)
            const float* w2q = w2 + (wf << 9);    // rows [wf*16, wf*16+16)
            const float* b2q = b2 + (wf << 4);
            float acc[16];
            #pragma unroll
            for (int i = 0; i < 16; ++i) acc[i] = b2q[i];
            #pragma unroll
            for (int c = 0; c < C1; ++c) {        // w1/b1/w2q uniform -> scalar loads
                float a = fmaf(w1[c * 3 + 2], rz,
                          fmaf(w1[c * 3 + 1], ry,
                          fmaf(w1[c * 3 + 0], rx, b1[c])));
                a = a > 0.f ? a : 0.f;
                #pragma unroll
                for (int i = 0; i < 16; ++i)
                    acc[i] = fmaf(w2q[i * 32 + c], a, acc[i]);
            }
            float* hrow = &hres[lane][wf << 4];
            #pragma unroll
            for (int i = 0; i < 16; ++i)
                hrow[i] = acc[i] > 0.f ? acc[i] : 0.f;   // plain store, unique writer
        }
        __syncthreads();
        // reduction: wave-uniform segments clipped to this chunk
        {
            int sl = s0A > cb ? s0A : cb;
            int sh = s0A + kA < cb + cq ? s0A + kA : cb + cq;
            for (int s2 = sl; s2 < sh; ++s2) mxA = fmaxf(mxA, hres[s2 - cb][oA]);
            sl = s0B > cb ? s0B : cb;
            sh = s0B + kB < cb + cq ? s0B + kB : cb + cq;
            for (int s2 = sl; s2 < sh; ++s2) mxB = fmaxf(mxB, hres[s2 - cb][oA]);
        }
        __syncthreads();                          // hres reused next chunk
    }

    // ---- write out: coalesced 64-wide rows + density ----
    out[(size_t)(p0 + plA) * (C2 + 1) + oA] = mxA;
    out[(size_t)(p0 + plB) * (C2 + 1) + oA] = mxB;
    if (tid < CB)
        out[(size_t)(p0 + tid) * (C2 + 1) + C2] = (float)kc[tid] * (1.0f / (float)C2);
}

// ================= fallback: R4 brute-force kernel (ws too small) =================
#define PBLK   16
#define CPW    4
#define BAND   2e-4f

__global__ __launch_bounds__(256, 8) void lse_fallback(
    const float* __restrict__ xyz,
    const float* __restrict__ w1, const float* __restrict__ b1,
    const float* __restrict__ w2, const float* __restrict__ b2,
    float* __restrict__ out)
{
    __shared__ int      lists[PBLK][NS];
    __shared__ int      counts[PBLK];
    __shared__ int      queue[PBLK * NS];
    __shared__ unsigned pooled[PBLK][C2 + 1];
    __shared__ float    ctr[PBLK][3];
    __shared__ float    dens[PBLK];
    __shared__ int      qtotal;

    const int tid = threadIdx.x, lane = tid & 63, wf = tid >> 6;
    const int pt0 = blockIdx.x * PBLK;
    const int bbase = (pt0 >> 12) << 12;

    for (int u = tid; u < PBLK * (C2 + 1); u += 256) ((unsigned*)pooled)[u] = 0u;
    if (tid < PBLK) {
        ctr[tid][0] = xyz[(size_t)(pt0 + tid) * 3 + 0];
        ctr[tid][1] = xyz[(size_t)(pt0 + tid) * 3 + 1];
        ctr[tid][2] = xyz[(size_t)(pt0 + tid) * 3 + 2];
    }
    const int c0 = pt0 + wf * CPW;
    float c2x[CPW], c2y[CPW], c2z[CPW], scc[CPW];
    #pragma unroll
    for (int j = 0; j < CPW; ++j) {
        const int g = __builtin_amdgcn_readfirstlane(c0 + j);
        const float cx = xyz[(size_t)g * 3 + 0];
        const float cy = xyz[(size_t)g * 3 + 1];
        const float cz = xyz[(size_t)g * 3 + 2];
        c2x[j] = -2.0f * cx; c2y[j] = -2.0f * cy; c2z[j] = -2.0f * cz;
        scc[j] = fmaf(cx, cx, fmaf(cy, cy, cz * cz)) - (R2C + BAND);
    }
    int cnt[CPW];
    #pragma unroll
    for (int j = 0; j < CPW; ++j) cnt[j] = 0;

    const float* xb = xyz + (size_t)bbase * 3;
    float qx = xb[lane * 3 + 0], qy = xb[lane * 3 + 1], qz = xb[lane * 3 + 2];
    for (int m0 = 0; m0 < BQ_N; m0 += 64) {
        float nqx = 0.f, nqy = 0.f, nqz = 0.f;
        if (m0 + 64 < BQ_N) {
            const int mn = m0 + 64 + lane;
            nqx = xb[mn * 3 + 0]; nqy = xb[mn * 3 + 1]; nqz = xb[mn * 3 + 2];
        }
        const float nsq = -fmaf(qx, qx, fmaf(qy, qy, qz * qz));
        float t[CPW]; unsigned long long msk[CPW];
        #pragma unroll
        for (int j = 0; j < CPW; ++j) {
            t[j] = fmaf(qx, c2x[j], fmaf(qy, c2y[j], fmaf(qz, c2z[j], scc[j])));
            msk[j] = __ballot(t[j] < nsq);
        }
        if ((msk[0] | msk[1] | msk[2] | msk[3]) != 0ull) {
            #pragma unroll
            for (int j = 0; j < CPW; ++j) {
                unsigned long long mask = msk[j];
                if (mask == 0ull) continue;
                const float u = t[j] - nsq;
                const bool nearb = (mask >> lane) & 1ull;
                const bool strict = u < (-2.0f * BAND);
                bool valid = strict;
                const unsigned long long mS = __ballot(strict);
                if (mS != mask) {
                    if (nearb && !strict) {
                        const double cx = -0.5 * (double)c2x[j];
                        const double cy = -0.5 * (double)c2y[j];
                        const double cz = -0.5 * (double)c2z[j];
                        const double dx = (double)qx - cx;
                        const double dy = (double)qy - cy;
                        const double dz = (double)qz - cz;
                        valid = (dx * dx + dy * dy + dz * dz) < 0.0625;
                    }
                    mask = __ballot(valid);
                    if (mask == 0ull) continue;
                }
                const unsigned mlo = (unsigned)mask, mhi = (unsigned)(mask >> 32);
                const int rank = __builtin_amdgcn_mbcnt_hi(
                                     mhi, __builtin_amdgcn_mbcnt_lo(mlo, 0));
                const int pos = cnt[j] + rank;
                if (valid && pos < NS) lists[wf * CPW + j][pos] = m0 + lane;
                cnt[j] += __popcll(mask);
            }
        }
        qx = nqx; qy = nqy; qz = nqz;
    }
    if (lane == 0) {
        #pragma unroll
        for (int j = 0; j < CPW; ++j) counts[wf * CPW + j] = cnt[j];
    }
    __syncthreads();
    if (tid < PBLK) {
        const int p = tid;
        const int ktot = counts[p];
        const int k = ktot < NS ? ktot : NS;
        dens[p] = (float)k * (1.0f / (float)C2);
        int incl = k;
        #pragma unroll
        for (int d = 1; d < PBLK; d <<= 1) {
            int v = __shfl_up(incl, d, 64);
            if (lane >= d) incl += v;
        }
        const int excl = incl - k;
        if (p == PBLK - 1) qtotal = incl;
        for (int j = 0; j < k; ++j) queue[excl + j] = (p << 12) | lists[p][j];
    }
    __syncthreads();
    const int Q = qtotal;
    for (int j = tid; j < Q; j += 256) {
        const int e = queue[j];
        const int p = e >> 12;
        const int idx = e & (BQ_N - 1);
        const float* nb = xyz + (size_t)(bbase + idx) * 3;
        const float rx = nb[0] - ctr[p][0];
        const float ry = nb[1] - ctr[p][1];
        const float rz = nb[2] - ctr[p][2];
        float h1[C1];
        #pragma unroll
        for (int cc = 0; cc < C1; ++cc) {
            float a = fmaf(w1[cc * 3 + 2], rz,
                      fmaf(w1[cc * 3 + 1], ry,
                      fmaf(w1[cc * 3 + 0], rx, b1[cc])));
            h1[cc] = a > 0.f ? a : 0.f;
        }
        #pragma unroll 2
        for (int o = 0; o < C2; ++o) {
            float acc = b2[o];
            #pragma unroll
            for (int i = 0; i < C1; ++i) acc = fmaf(w2[o * C1 + i], h1[i], acc);
            acc = acc > 0.f ? acc : 0.f;
            atomicMax(&pooled[p][o], __float_as_uint(acc));
        }
    }
    __syncthreads();
    for (int u = tid; u < PBLK * (C2 + 1); u += 256) {
        const int p = u / (C2 + 1);
        const int cc = u % (C2 + 1);
        const float v = (cc < C2) ? __uint_as_float(pooled[p][cc]) : dens[p];
        out[(size_t)(pt0 + p) * (C2 + 1) + cc] = v;
    }
}

extern "C" void kernel_launch(void* const* d_in, const int* in_sizes, int n_in,
                              void* d_out, int out_size, void* d_ws, size_t ws_size,
                              hipStream_t stream) {
    const float* xyz = (const float*)d_in[0];
    const float* w1  = (const float*)d_in[1];
    const float* b1  = (const float*)d_in[2];
    const float* w2  = (const float*)d_in[3];
    const float* b2  = (const float*)d_in[4];
    float* out = (float*)d_out;

    // workspace layout (u32 units):
    // done[4] | counts[NCELLS] | partial[NCELLS] | cellstart[NCELLS+16] |
    // blocksum[256] | blockoff[256] | pcell[NPTS] | ppos[NPTS] | pts[4*NPTS]
    const size_t need = (size_t)(4 + 3 * NCELLS + 16 + 512 + 2 * NPTS + 4 * NPTS) * 4;

    if (ws_size >= need) {
        unsigned* wsu       = (unsigned*)d_ws;
        unsigned* done      = wsu;                      // 4 (only [0] used)
        unsigned* counts    = done + 4;                 // NCELLS
        unsigned* partial   = counts + NCELLS;          // NCELLS
        unsigned* cellstart = partial + NCELLS;         // NCELLS + 16 (sentinel)
        unsigned* blocksum  = cellstart + NCELLS + 16;  // 256
        unsigned* blockoff  = blocksum + 256;           // 256
        unsigned* pcell     = blockoff + 256;           // NPTS
        unsigned* ppos      = pcell + NPTS;             // NPTS
        float4*   pts       = (float4*)(ppos + NPTS);   // NPTS * 4 dwords (16B-aligned)

        hipMemsetAsync(done, 0, (size_t)(4 + NCELLS) * 4, stream);  // done + counts
        grid_count<<<NPTS / 256, 256, 0, stream>>>(xyz, counts, pcell, ppos);
        scan1f<<<NBLK2, SCAN_B, 0, stream>>>(counts, partial, blocksum, blockoff, done);
        grid_scatterF<<<NCELLS / 256, 256, 0, stream>>>(xyz, partial, blockoff,
                                                        pcell, ppos, cellstart, pts);
        lse_grid7<<<NPTS / CB, 256, 0, stream>>>(xyz, cellstart, pts,
                                                 w1, b1, w2, b2, out);
    } else {
        lse_fallback<<<NPTS / PBLK, 256, 0, stream>>>(xyz, w1, b1, w2, b2, out);
    }
}

// Round 12
// 254.226 us; speedup vs baseline: 2.3000x; 1.6726x over previous
//
#include <hip/hip_runtime.h>

// Problem constants (from reference)
#define BQ_B   8
#define BQ_N   4096
#define NS     32
#define C1     32
#define C2     64
#define R2C    0.0625f
#define NPTS   (BQ_B * BQ_N)

// ---- spatial grid ----
#define GD     32                  // cells per dim, cell size 0.25, origin -4 (clamped)
#define NC_B   (GD * GD * GD)      // 32768 cells per batch
#define NCELLS (BQ_B * NC_B)       // 262144 total
#define SCAN_B 1024
#define NBLK2  (NCELLS / SCAN_B)   // 256

__device__ __forceinline__ int cell_coord(float x) {
    int i = (int)floorf((x + 4.0f) * 4.0f);
    return i < 0 ? 0 : (i > GD - 1 ? GD - 1 : i);
}

// ---------- grid build ----------
__global__ __launch_bounds__(256) void grid_count(
    const float* __restrict__ xyz, unsigned* __restrict__ counts,
    unsigned* __restrict__ pcell, unsigned* __restrict__ ppos)
{
    const int i = blockIdx.x * 256 + threadIdx.x;
    const float x = xyz[3 * i], y = xyz[3 * i + 1], z = xyz[3 * i + 2];
    const int ix = cell_coord(x), iy = cell_coord(y), iz = cell_coord(z);
    const unsigned cid = (unsigned)(((i >> 12) * GD + iz) * GD + iy) * GD + ix;
    pcell[i] = cid;
    ppos[i] = atomicAdd(&counts[cid], 1u);
}

// fused: per-block exclusive scan + (last block) top-level scan of blocksums
__global__ __launch_bounds__(1024) void scan1f(
    const unsigned* __restrict__ counts, unsigned* __restrict__ partial,
    unsigned* __restrict__ blocksum, unsigned* __restrict__ blockoff,
    unsigned* __restrict__ done)
{
    __shared__ unsigned wsum[16];
    __shared__ unsigned ws2[4];
    __shared__ unsigned lastv;
    const int tid = threadIdx.x, lane = tid & 63, w = tid >> 6;
    const int g = blockIdx.x * 1024 + tid;
    const unsigned v = counts[g];
    unsigned incl = v;
    #pragma unroll
    for (int d = 1; d < 64; d <<= 1) {
        unsigned t = __shfl_up(incl, d, 64);
        if (lane >= d) incl += t;
    }
    if (lane == 63) wsum[w] = incl;
    __syncthreads();
    if (w == 0 && lane < 16) {
        const unsigned s = wsum[lane];
        unsigned si = s;
        #pragma unroll
        for (int d = 1; d < 16; d <<= 1) {
            unsigned t = __shfl_up(si, d, 64);
            if (lane >= d) si += t;
        }
        wsum[lane] = si - s;
        if (lane == 15) blocksum[blockIdx.x] = si;
    }
    __syncthreads();
    partial[g] = wsum[w] + incl - v;

    // ---- last-block does the 256-entry top-level scan ----
    __threadfence();
    __syncthreads();
    if (tid == 0) lastv = atomicAdd(done, 1u);   // device-scope
    __syncthreads();
    if (lastv == NBLK2 - 1) {              // block-uniform branch
        __threadfence();                   // acquire side
        unsigned bv = 0, bincl = 0;
        if (tid < NBLK2) {
            bv = blocksum[tid];
            bincl = bv;
            #pragma unroll
            for (int d = 1; d < 64; d <<= 1) {
                unsigned t = __shfl_up(bincl, d, 64);
                if (lane >= d) bincl += t;
            }
            if (lane == 63) ws2[w] = bincl;
        }
        __syncthreads();
        if (tid < NBLK2) {
            unsigned off = 0;
            #pragma unroll
            for (int j = 0; j < 4; ++j) if (j < w) off += ws2[j];
            blockoff[tid] = off + bincl - bv;
        }
    }
}

// fused: cellstart finalize (all 262144 cells) + point scatter (first NPTS threads)
__global__ __launch_bounds__(256) void grid_scatterF(
    const float* __restrict__ xyz,
    const unsigned* __restrict__ partial, const unsigned* __restrict__ blockoff,
    const unsigned* __restrict__ pcell, const unsigned* __restrict__ ppos,
    unsigned* __restrict__ cellstart, float4* __restrict__ pts)
{
    const int g = blockIdx.x * 256 + threadIdx.x;   // 1024 blocks
    cellstart[g] = partial[g] + blockoff[g >> 10];
    if (g == 0) cellstart[NCELLS] = NPTS;
    if (g < NPTS) {
        const unsigned cid = pcell[g];
        const unsigned pos = partial[cid] + blockoff[cid >> 10] + ppos[g];
        float4 v;
        v.x = xyz[3 * g];
        v.y = xyz[3 * g + 1];
        v.z = xyz[3 * g + 2];
        v.w = __uint_as_float((unsigned)(g & (BQ_N - 1)));
        pts[pos] = v;
    }
}

// ---------- main: grid ball-query + atomic-free quarter-split MLP ----------
#define CB  8    // centers per block (grid 4096)
#define CW  2    // centers per wave
#define MCH 64   // MLP chunk samples

// launch_bounds(256,4): 128-VGPR cap -> no spill; HW occupancy still rises to
// 8 blocks/CU if actual usage <= 64 VGPRs. (256,8) forced a 64-VGPR cap and
// spilled ~450B/thread to scratch (R10/R11: FETCH/WRITE blew up to 100s of MB).
__global__ __launch_bounds__(256, 4) void lse_grid8(
    const float* __restrict__ xyz,
    const unsigned* __restrict__ cellstart,
    const float4* __restrict__ pts,
    const float* __restrict__ w1, const float* __restrict__ b1,
    const float* __restrict__ w2, const float* __restrict__ b2,
    float* __restrict__ out)
{
    __shared__ unsigned cand[4][64];          // per-wave candidate src positions
    __shared__ unsigned queue[4][CW * NS];    // compact entries: (pl<<20)|src
    __shared__ int      qlen[4];
    __shared__ float    ctr[CB][3];
    __shared__ unsigned kc[CB];               // k per center
    __shared__ unsigned qsl[CB];              // wave-local queue start of center pl
    __shared__ float    hres[MCH][C2 + 1];    // h2 results: [chunk-sample][o], stride 65

    const int tid  = threadIdx.x, lane = tid & 63, wf = tid >> 6;
    const int p0   = blockIdx.x * CB;         // never straddles a batch
    const int b    = p0 >> 12;

    // hoisted wave-uniform center coords (scalar loads)
    float scx[CW], scy[CW], scz[CW];
    #pragma unroll
    for (int jc = 0; jc < CW; ++jc) {
        const int g = __builtin_amdgcn_readfirstlane(p0 + wf * CW + jc);
        float x = xyz[3 * g], y = xyz[3 * g + 1], z = xyz[3 * g + 2];
        scx[jc] = __int_as_float(__builtin_amdgcn_readfirstlane(__float_as_int(x)));
        scy[jc] = __int_as_float(__builtin_amdgcn_readfirstlane(__float_as_int(y)));
        scz[jc] = __int_as_float(__builtin_amdgcn_readfirstlane(__float_as_int(z)));
    }
    if (lane == 0) {
        #pragma unroll
        for (int jc = 0; jc < CW; ++jc) {
            ctr[wf * CW + jc][0] = scx[jc];
            ctr[wf * CW + jc][1] = scy[jc];
            ctr[wf * CW + jc][2] = scz[jc];
        }
    }

    int myqlen = 0;
    #pragma unroll
    for (int jc = 0; jc < CW; ++jc) {
        const int pl = wf * CW + jc;
        const float cx = scx[jc], cy = scy[jc], cz = scz[jc];
        const int icx = __builtin_amdgcn_readfirstlane(cell_coord(cx));
        const int icy = __builtin_amdgcn_readfirstlane(cell_coord(cy));
        const int icz = __builtin_amdgcn_readfirstlane(cell_coord(cz));
        const int lo = icx > 0 ? icx - 1 : 0;
        const int hi = icx < GD - 1 ? icx + 1 : GD - 1;

        // 9 candidate ranges from wave-uniform scalar loads
        unsigned st[9], cn[9], of[9];
        unsigned T = 0;
        #pragma unroll
        for (int r = 0; r < 9; ++r) {
            const int dz = r / 3 - 1, dy = r % 3 - 1;
            const int rz = icz + dz, ry = icy + dy;
            const bool ok = (rz >= 0) & (rz < GD) & (ry >= 0) & (ry < GD);
            const int rzc = rz < 0 ? 0 : (rz > GD - 1 ? GD - 1 : rz);
            const int ryc = ry < 0 ? 0 : (ry > GD - 1 ? GD - 1 : ry);
            const int cbase = ((b * GD + rzc) * GD + ryc) * GD;
            const unsigned s = cellstart[cbase + lo];
            const unsigned e = cellstart[cbase + hi + 1];
            st[r] = s;
            cn[r] = ok ? e - s : 0u;
            of[r] = T;
            T += cn[r];
        }

        int kcur = 0;
        for (unsigned tb = 0; tb < T; tb += 64) {
            const unsigned t = tb + (unsigned)lane;
            unsigned src = 0;
            #pragma unroll
            for (int r = 0; r < 9; ++r) {          // SGPR operands, pure VALU
                const unsigned d = t - of[r];
                if (d < cn[r]) src = st[r] + d;
            }
            const bool inb = t < T;
            const float4 q4 = pts[src];            // one dwordx4 gather
            const float dx = q4.x - cx, dy = q4.y - cy, dz = q4.z - cz;
            const float d2 = fmaf(dz, dz, fmaf(dy, dy, dx * dx));
            const bool nearb  = inb && (d2 < R2C + 1e-5f);
            const bool strict = inb && (d2 < R2C - 1e-5f);
            bool valid = strict;
            if (nearb && !strict) {                // rare: exact fp64 adjudication
                const double ddx = (double)q4.x - (double)cx;
                const double ddy = (double)q4.y - (double)cy;
                const double ddz = (double)q4.z - (double)cz;
                valid = (ddx * ddx + ddy * ddy + ddz * ddz) < 0.0625;
            }
            const unsigned long long mask = __ballot(valid);
            if (mask) {
                const unsigned mlo = (unsigned)mask, mhi = (unsigned)(mask >> 32);
                const int rank = __builtin_amdgcn_mbcnt_hi(
                                     mhi, __builtin_amdgcn_mbcnt_lo(mlo, 0));
                const int pos = kcur + rank;
                if (valid && pos < 64) cand[wf][pos] = src;  // P(ktot>64) negligible
                kcur += __popcll(mask);
            }
        }

        const int k = kcur < NS ? kcur : NS;       // == unique_cnt
        if (lane == 0) { kc[pl] = (unsigned)k; qsl[pl] = (unsigned)myqlen; }

        int slot = lane;
        if (kcur > NS) {                           // rare: pick 32 smallest idx
            unsigned key = 0x7FFFFFFFu;
            if (lane < kcur && lane < 64) {
                const unsigned qi = __float_as_uint(pts[cand[wf][lane]].w);
                key = (qi << 6) | (unsigned)lane;
            }
            #pragma unroll
            for (int size = 2; size <= 64; size <<= 1) {
                #pragma unroll
                for (int stride = size >> 1; stride > 0; stride >>= 1) {
                    const unsigned partner = (unsigned)__shfl_xor((int)key, stride, 64);
                    const bool keepmin = ((lane & stride) == 0) == ((lane & size) == 0);
                    key = keepmin ? (key < partner ? key : partner)
                                  : (key > partner ? key : partner);
                }
            }
            slot = (int)(key & 63u);
        }
        if (lane < k)
            queue[wf][myqlen + lane] = ((unsigned)pl << 20) | cand[wf][slot];
        myqlen += k;
    }
    if (lane == 0) qlen[wf] = myqlen;
    __syncthreads();

    // ---- MLP: wave = output quarter, lane = chunk sample; no atomics ----
    const int q0 = qlen[0], q1 = qlen[1], q2 = qlen[2], q3 = qlen[3];
    const int o1 = q0, o2 = q0 + q1, o3 = o2 + q2;
    const int Qtot = o3 + q3;

    // owners: thread reduces (plA, oA) and (plB, oA)
    const int plA = tid >> 6;                     // 0..3 (== wf)
    const int oA  = lane;
    const int plB = plA + 4;                      // 4..7
    const int s0A = ((tid & 128) ? o1 : 0)  + (int)qsl[plA];
    const int s0B = ((tid & 128) ? o3 : o2) + (int)qsl[plB];
    const int kA  = (int)kc[plA];
    const int kB  = (int)kc[plB];
    float mxA = 0.f, mxB = 0.f;                   // relu outputs >= 0

    for (int cb = 0; cb < Qtot; cb += MCH) {
        const int cq = Qtot - cb < MCH ? Qtot - cb : MCH;
        const int s = cb + lane;                  // this lane's sample
        if (lane < cq) {
            int w, loc;
            if (s < o1)      { w = 0; loc = s; }
            else if (s < o2) { w = 1; loc = s - o1; }
            else if (s < o3) { w = 2; loc = s - o2; }
            else             { w = 3; loc = s - o3; }
            const unsigned e = queue[w][loc];
            const int pl = (int)(e >> 20);
            const unsigned src = e & 0xFFFFFu;
            const float4 f4 = pts[src];           // L1/L2-hot gather
            const float rx = f4.x - ctr[pl][0];
            const float ry = f4.y - ctr[pl][1];
            const float rz = f4.z - ctr[pl][2];

            // c-outer accumulate form: live state = acc[16]
            const float* w2q = w2 + (wf << 9);    // rows [wf*16, wf*16+16)
            const float* b2q = b2 + (wf << 4);
            float acc[16];
            #pragma unroll
            for (int i = 0; i < 16; ++i) acc[i] = b2q[i];
            #pragma unroll
            for (int c = 0; c < C1; ++c) {        // w1/b1/w2q uniform -> scalar loads
                float a = fmaf(w1[c * 3 + 2], rz,
                          fmaf(w1[c * 3 + 1], ry,
                          fmaf(w1[c * 3 + 0], rx, b1[c])));
                a = a > 0.f ? a : 0.f;
                #pragma unroll
                for (int i = 0; i < 16; ++i)
                    acc[i] = fmaf(w2q[i * 32 + c], a, acc[i]);
            }
            float* hrow = &hres[lane][wf << 4];
            #pragma unroll
            for (int i = 0; i < 16; ++i)
                hrow[i] = acc[i] > 0.f ? acc[i] : 0.f;   // plain store, unique writer
        }
        __syncthreads();
        // reduction: wave-uniform segments clipped to this chunk
        {
            int sl = s0A > cb ? s0A : cb;
            int sh = s0A + kA < cb + cq ? s0A + kA : cb + cq;
            for (int s2 = sl; s2 < sh; ++s2) mxA = fmaxf(mxA, hres[s2 - cb][oA]);
            sl = s0B > cb ? s0B : cb;
            sh = s0B + kB < cb + cq ? s0B + kB : cb + cq;
            for (int s2 = sl; s2 < sh; ++s2) mxB = fmaxf(mxB, hres[s2 - cb][oA]);
        }
        __syncthreads();                          // hres reused next chunk
    }

    // ---- write out: coalesced 64-wide rows + density ----
    out[(size_t)(p0 + plA) * (C2 + 1) + oA] = mxA;
    out[(size_t)(p0 + plB) * (C2 + 1) + oA] = mxB;
    if (tid < CB)
        out[(size_t)(p0 + tid) * (C2 + 1) + C2] = (float)kc[tid] * (1.0f / (float)C2);
}

// ================= fallback: R4 brute-force kernel (ws too small) =================
#define PBLK   16
#define CPW    4
#define BAND   2e-4f

__global__ __launch_bounds__(256, 4) void lse_fallback(
    const float* __restrict__ xyz,
    const float* __restrict__ w1, const float* __restrict__ b1,
    const float* __restrict__ w2, const float* __restrict__ b2,
    float* __restrict__ out)
{
    __shared__ int      lists[PBLK][NS];
    __shared__ int      counts[PBLK];
    __shared__ int      queue[PBLK * NS];
    __shared__ unsigned pooled[PBLK][C2 + 1];
    __shared__ float    ctr[PBLK][3];
    __shared__ float    dens[PBLK];
    __shared__ int      qtotal;

    const int tid = threadIdx.x, lane = tid & 63, wf = tid >> 6;
    const int pt0 = blockIdx.x * PBLK;
    const int bbase = (pt0 >> 12) << 12;

    for (int u = tid; u < PBLK * (C2 + 1); u += 256) ((unsigned*)pooled)[u] = 0u;
    if (tid < PBLK) {
        ctr[tid][0] = xyz[(size_t)(pt0 + tid) * 3 + 0];
        ctr[tid][1] = xyz[(size_t)(pt0 + tid) * 3 + 1];
        ctr[tid][2] = xyz[(size_t)(pt0 + tid) * 3 + 2];
    }
    const int c0 = pt0 + wf * CPW;
    float c2x[CPW], c2y[CPW], c2z[CPW], scc[CPW];
    #pragma unroll
    for (int j = 0; j < CPW; ++j) {
        const int g = __builtin_amdgcn_readfirstlane(c0 + j);
        const float cx = xyz[(size_t)g * 3 + 0];
        const float cy = xyz[(size_t)g * 3 + 1];
        const float cz = xyz[(size_t)g * 3 + 2];
        c2x[j] = -2.0f * cx; c2y[j] = -2.0f * cy; c2z[j] = -2.0f * cz;
        scc[j] = fmaf(cx, cx, fmaf(cy, cy, cz * cz)) - (R2C + BAND);
    }
    int cnt[CPW];
    #pragma unroll
    for (int j = 0; j < CPW; ++j) cnt[j] = 0;

    const float* xb = xyz + (size_t)bbase * 3;
    float qx = xb[lane * 3 + 0], qy = xb[lane * 3 + 1], qz = xb[lane * 3 + 2];
    for (int m0 = 0; m0 < BQ_N; m0 += 64) {
        float nqx = 0.f, nqy = 0.f, nqz = 0.f;
        if (m0 + 64 < BQ_N) {
            const int mn = m0 + 64 + lane;
            nqx = xb[mn * 3 + 0]; nqy = xb[mn * 3 + 1]; nqz = xb[mn * 3 + 2];
        }
        const float nsq = -fmaf(qx, qx, fmaf(qy, qy, qz * qz));
        float t[CPW]; unsigned long long msk[CPW];
        #pragma unroll
        for (int j = 0; j < CPW; ++j) {
            t[j] = fmaf(qx, c2x[j], fmaf(qy, c2y[j], fmaf(qz, c2z[j], scc[j])));
            msk[j] = __ballot(t[j] < nsq);
        }
        if ((msk[0] | msk[1] | msk[2] | msk[3]) != 0ull) {
            #pragma unroll
            for (int j = 0; j < CPW; ++j) {
                unsigned long long mask = msk[j];
                if (mask == 0ull) continue;
                const float u = t[j] - nsq;
                const bool nearb = (mask >> lane) & 1ull;
                const bool strict = u < (-2.0f * BAND);
                bool valid = strict;
                const unsigned long long mS = __ballot(strict);
                if (mS != mask) {
                    if (nearb && !strict) {
                        const double cx = -0.5 * (double)c2x[j];
                        const double cy = -0.5 * (double)c2y[j];
                        const double cz = -0.5 * (double)c2z[j];
                        const double dx = (double)qx - cx;
                        const double dy = (double)qy - cy;
                        const double dz = (double)qz - cz;
                        valid = (dx * dx + dy * dy + dz * dz) < 0.0625;
                    }
                    mask = __ballot(valid);
                    if (mask == 0ull) continue;
                }
                const unsigned mlo = (unsigned)mask, mhi = (unsigned)(mask >> 32);
                const int rank = __builtin_amdgcn_mbcnt_hi(
                                     mhi, __builtin_amdgcn_mbcnt_lo(mlo, 0));
                const int pos = cnt[j] + rank;
                if (valid && pos < NS) lists[wf * CPW + j][pos] = m0 + lane;
                cnt[j] += __popcll(mask);
            }
        }
        qx = nqx; qy = nqy; qz = nqz;
    }
    if (lane == 0) {
        #pragma unroll
        for (int j = 0; j < CPW; ++j) counts[wf * CPW + j] = cnt[j];
    }
    __syncthreads();
    if (tid < PBLK) {
        const int p = tid;
        const int ktot = counts[p];
        const int k = ktot < NS ? ktot : NS;
        dens[p] = (float)k * (1.0f / (float)C2);
        int incl = k;
        #pragma unroll
        for (int d = 1; d < PBLK; d <<= 1) {
            int v = __shfl_up(incl, d, 64);
            if (lane >= d) incl += v;
        }
        const int excl = incl - k;
        if (p == PBLK - 1) qtotal = incl;
        for (int j = 0; j < k; ++j) queue[excl + j] = (p << 12) | lists[p][j];
    }
    __syncthreads();
    const int Q = qtotal;
    for (int j = tid; j < Q; j += 256) {
        const int e = queue[j];
        const int p = e >> 12;
        const int idx = e & (BQ_N - 1);
        const float* nb = xyz + (size_t)(bbase + idx) * 3;
        const float rx = nb[0] - ctr[p][0];
        const float ry = nb[1] - ctr[p][1];
        const float rz = nb[2] - ctr[p][2];
        float h1[C1];
        #pragma unroll
        for (int cc = 0; cc < C1; ++cc) {
            float a = fmaf(w1[cc * 3 + 2], rz,
                      fmaf(w1[cc * 3 + 1], ry,
                      fmaf(w1[cc * 3 + 0], rx, b1[cc])));
            h1[cc] = a > 0.f ? a : 0.f;
        }
        #pragma unroll 2
        for (int o = 0; o < C2; ++o) {
            float acc = b2[o];
            #pragma unroll
            for (int i = 0; i < C1; ++i) acc = fmaf(w2[o * C1 + i], h1[i], acc);
            acc = acc > 0.f ? acc : 0.f;
            atomicMax(&pooled[p][o], __float_as_uint(acc));
        }
    }
    __syncthreads();
    for (int u = tid; u < PBLK * (C2 + 1); u += 256) {
        const int p = u / (C2 + 1);
        const int cc = u % (C2 + 1);
        const float v = (cc < C2) ? __uint_as_float(pooled[p][cc]) : dens[p];
        out[(size_t)(pt0 + p) * (C2 + 1) + cc] = v;
    }
}

extern "C" void kernel_launch(void* const* d_in, const int* in_sizes, int n_in,
                              void* d_out, int out_size, void* d_ws, size_t ws_size,
                              hipStream_t stream) {
    const float* xyz = (const float*)d_in[0];
    const float* w1  = (const float*)d_in[1];
    const float* b1  = (const float*)d_in[2];
    const float* w2  = (const float*)d_in[3];
    const float* b2  = (const float*)d_in[4];
    float* out = (float*)d_out;

    // workspace layout (u32 units):
    // done[4] | counts[NCELLS] | partial[NCELLS] | cellstart[NCELLS+16] |
    // blocksum[256] | blockoff[256] | pcell[NPTS] | ppos[NPTS] | pts[4*NPTS]
    const size_t need = (size_t)(4 + 3 * NCELLS + 16 + 512 + 2 * NPTS + 4 * NPTS) * 4;

    if (ws_size >= need) {
        unsigned* wsu       = (unsigned*)d_ws;
        unsigned* done      = wsu;                      // 4 (only [0] used)
        unsigned* counts    = done + 4;                 // NCELLS
        unsigned* partial   = counts + NCELLS;          // NCELLS
        unsigned* cellstart = partial + NCELLS;         // NCELLS + 16 (sentinel)
        unsigned* blocksum  = cellstart + NCELLS + 16;  // 256
        unsigned* blockoff  = blocksum + 256;           // 256
        unsigned* pcell     = blockoff + 256;           // NPTS
        unsigned* ppos      = pcell + NPTS;             // NPTS
        float4*   pts       = (float4*)(ppos + NPTS);   // NPTS * 4 dwords (16B-aligned)

        hipMemsetAsync(done, 0, (size_t)(4 + NCELLS) * 4, stream);  // done + counts
        grid_count<<<NPTS / 256, 256, 0, stream>>>(xyz, counts, pcell, ppos);
        scan1f<<<NBLK2, SCAN_B, 0, stream>>>(counts, partial, blocksum, blockoff, done);
        grid_scatterF<<<NCELLS / 256, 256, 0, stream>>>(xyz, partial, blockoff,
                                                        pcell, ppos, cellstart, pts);
        lse_grid8<<<NPTS / CB, 256, 0, stream>>>(xyz, cellstart, pts,
                                                 w1, b1, w2, b2, out);
    } else {
        lse_fallback<<<NPTS / PBLK, 256, 0, stream>>>(xyz, w1, b1, w2, b2, out);
    }
}

// Round 13
// 189.606 us; speedup vs baseline: 3.0839x; 1.3408x over previous
//
#include <hip/hip_runtime.h>

// Problem constants (from reference)
#define BQ_B   8
#define BQ_N   4096
#define NS     32
#define C1     32
#define C2     64
#define R2C    0.0625f
#define NPTS   (BQ_B * BQ_N)

// ---- spatial grid ----
#define GD     32                  // cells per dim, cell size 0.25, origin -4 (clamped)
#define NC_B   (GD * GD * GD)      // 32768 cells per batch
#define NCELLS (BQ_B * NC_B)       // 262144 total
#define SCAN_B 1024
#define NBLK2  (NCELLS / SCAN_B)   // 256

__device__ __forceinline__ int cell_coord(float x) {
    int i = (int)floorf((x + 4.0f) * 4.0f);
    return i < 0 ? 0 : (i > GD - 1 ? GD - 1 : i);
}

// ---------- grid build ----------
__global__ __launch_bounds__(256) void grid_count(
    const float* __restrict__ xyz, unsigned* __restrict__ counts,
    unsigned* __restrict__ pcell, unsigned* __restrict__ ppos)
{
    const int i = blockIdx.x * 256 + threadIdx.x;
    const float x = xyz[3 * i], y = xyz[3 * i + 1], z = xyz[3 * i + 2];
    const int ix = cell_coord(x), iy = cell_coord(y), iz = cell_coord(z);
    const unsigned cid = (unsigned)(((i >> 12) * GD + iz) * GD + iy) * GD + ix;
    pcell[i] = cid;
    ppos[i] = atomicAdd(&counts[cid], 1u);
}

// fused: per-block exclusive scan + (last block) top-level scan of blocksums
__global__ __launch_bounds__(1024) void scan1f(
    const unsigned* __restrict__ counts, unsigned* __restrict__ partial,
    unsigned* __restrict__ blocksum, unsigned* __restrict__ blockoff,
    unsigned* __restrict__ done)
{
    __shared__ unsigned wsum[16];
    __shared__ unsigned ws2[4];
    __shared__ unsigned lastv;
    const int tid = threadIdx.x, lane = tid & 63, w = tid >> 6;
    const int g = blockIdx.x * 1024 + tid;
    const unsigned v = counts[g];
    unsigned incl = v;
    #pragma unroll
    for (int d = 1; d < 64; d <<= 1) {
        unsigned t = __shfl_up(incl, d, 64);
        if (lane >= d) incl += t;
    }
    if (lane == 63) wsum[w] = incl;
    __syncthreads();
    if (w == 0 && lane < 16) {
        const unsigned s = wsum[lane];
        unsigned si = s;
        #pragma unroll
        for (int d = 1; d < 16; d <<= 1) {
            unsigned t = __shfl_up(si, d, 64);
            if (lane >= d) si += t;
        }
        wsum[lane] = si - s;
        if (lane == 15) blocksum[blockIdx.x] = si;
    }
    __syncthreads();
    partial[g] = wsum[w] + incl - v;

    // ---- last-block does the 256-entry top-level scan ----
    __threadfence();
    __syncthreads();
    if (tid == 0) lastv = atomicAdd(done, 1u);   // device-scope
    __syncthreads();
    if (lastv == NBLK2 - 1) {              // block-uniform branch
        __threadfence();                   // acquire side
        unsigned bv = 0, bincl = 0;
        if (tid < NBLK2) {
            bv = blocksum[tid];
            bincl = bv;
            #pragma unroll
            for (int d = 1; d < 64; d <<= 1) {
                unsigned t = __shfl_up(bincl, d, 64);
                if (lane >= d) bincl += t;
            }
            if (lane == 63) ws2[w] = bincl;
        }
        __syncthreads();
        if (tid < NBLK2) {
            unsigned off = 0;
            #pragma unroll
            for (int j = 0; j < 4; ++j) if (j < w) off += ws2[j];
            blockoff[tid] = off + bincl - bv;
        }
    }
}

// fused: cellstart finalize (all 262144 cells) + point scatter (first NPTS threads)
__global__ __launch_bounds__(256) void grid_scatterF(
    const float* __restrict__ xyz,
    const unsigned* __restrict__ partial, const unsigned* __restrict__ blockoff,
    const unsigned* __restrict__ pcell, const unsigned* __restrict__ ppos,
    unsigned* __restrict__ cellstart, float4* __restrict__ pts)
{
    const int g = blockIdx.x * 256 + threadIdx.x;   // 1024 blocks
    cellstart[g] = partial[g] + blockoff[g >> 10];
    if (g == 0) cellstart[NCELLS] = NPTS;
    if (g < NPTS) {
        const unsigned cid = pcell[g];
        const unsigned pos = partial[cid] + blockoff[cid >> 10] + ppos[g];
        float4 v;
        v.x = xyz[3 * g];
        v.y = xyz[3 * g + 1];
        v.z = xyz[3 * g + 2];
        v.w = __uint_as_float((unsigned)(g & (BQ_N - 1)));
        pts[pos] = v;
    }
}

// ---------- main: R9's proven kernel (grid ball-query + o-split atomicMax MLP) ----------
#define CB 8    // centers per block (grid 4096 -> dynamic balance)
#define CW 2    // centers per wave

__global__ __launch_bounds__(256, 8) void lse_grid5(
    const float* __restrict__ xyz,
    const unsigned* __restrict__ cellstart,
    const float4* __restrict__ pts,
    const float* __restrict__ w1, const float* __restrict__ b1,
    const float* __restrict__ w2, const float* __restrict__ b2,
    float* __restrict__ out)
{
    __shared__ unsigned cand[4][64];          // per-wave candidate src positions
    __shared__ unsigned queue[4][CW * NS];    // compact entries: (pl<<20)|src
    __shared__ int      qlen[4];
    __shared__ unsigned pooled[CB][C2 + 1];   // stride 65: bank=(pl+o)%32
    __shared__ float    ctr[CB][3];
    __shared__ unsigned kc[CB];               // k per center (density)

    const int tid  = threadIdx.x, lane = tid & 63, wf = tid >> 6;
    const int p0   = blockIdx.x * CB;         // never straddles a batch
    const int b    = p0 >> 12;

    for (int u = tid; u < CB * (C2 + 1); u += 256) ((unsigned*)pooled)[u] = 0u;

    // hoisted wave-uniform center coords (scalar loads, issued early)
    float scx[CW], scy[CW], scz[CW];
    #pragma unroll
    for (int jc = 0; jc < CW; ++jc) {
        const int g = __builtin_amdgcn_readfirstlane(p0 + wf * CW + jc);
        float x = xyz[3 * g], y = xyz[3 * g + 1], z = xyz[3 * g + 2];
        scx[jc] = __int_as_float(__builtin_amdgcn_readfirstlane(__float_as_int(x)));
        scy[jc] = __int_as_float(__builtin_amdgcn_readfirstlane(__float_as_int(y)));
        scz[jc] = __int_as_float(__builtin_amdgcn_readfirstlane(__float_as_int(z)));
    }
    if (lane == 0) {
        #pragma unroll
        for (int jc = 0; jc < CW; ++jc) {
            ctr[wf * CW + jc][0] = scx[jc];
            ctr[wf * CW + jc][1] = scy[jc];
            ctr[wf * CW + jc][2] = scz[jc];
        }
    }

    int myqlen = 0;
    #pragma unroll
    for (int jc = 0; jc < CW; ++jc) {         // full unroll: s_loads overlap
        const int pl = wf * CW + jc;          // block-local center
        const float cx = scx[jc], cy = scy[jc], cz = scz[jc];
        const int icx = __builtin_amdgcn_readfirstlane(cell_coord(cx));
        const int icy = __builtin_amdgcn_readfirstlane(cell_coord(cy));
        const int icz = __builtin_amdgcn_readfirstlane(cell_coord(cz));
        const int lo = icx > 0 ? icx - 1 : 0;
        const int hi = icx < GD - 1 ? icx + 1 : GD - 1;

        // 9 candidate ranges from wave-uniform scalar loads
        unsigned st[9], cn[9], of[9];
        unsigned T = 0;
        #pragma unroll
        for (int r = 0; r < 9; ++r) {
            const int dz = r / 3 - 1, dy = r % 3 - 1;
            const int rz = icz + dz, ry = icy + dy;
            const bool ok = (rz >= 0) & (rz < GD) & (ry >= 0) & (ry < GD);
            const int rzc = rz < 0 ? 0 : (rz > GD - 1 ? GD - 1 : rz);
            const int ryc = ry < 0 ? 0 : (ry > GD - 1 ? GD - 1 : ry);
            const int cbase = ((b * GD + rzc) * GD + ryc) * GD;
            const unsigned s = cellstart[cbase + lo];
            const unsigned e = cellstart[cbase + hi + 1];
            st[r] = s;
            cn[r] = ok ? e - s : 0u;
            of[r] = T;
            T += cn[r];
        }

        int kcur = 0;
        for (unsigned tb = 0; tb < T; tb += 64) {
            const unsigned t = tb + (unsigned)lane;
            unsigned src = 0;
            #pragma unroll
            for (int r = 0; r < 9; ++r) {          // SGPR operands, pure VALU
                const unsigned d = t - of[r];
                if (d < cn[r]) src = st[r] + d;
            }
            const bool inb = t < T;
            const float4 q4 = pts[src];            // one dwordx4 gather
            const float dx = q4.x - cx, dy = q4.y - cy, dz = q4.z - cz;
            const float d2 = fmaf(dz, dz, fmaf(dy, dy, dx * dx));
            const bool nearb  = inb && (d2 < R2C + 1e-5f);
            const bool strict = inb && (d2 < R2C - 1e-5f);
            bool valid = strict;
            if (nearb && !strict) {                // rare: exact fp64 adjudication
                const double ddx = (double)q4.x - (double)cx;
                const double ddy = (double)q4.y - (double)cy;
                const double ddz = (double)q4.z - (double)cz;
                valid = (ddx * ddx + ddy * ddy + ddz * ddz) < 0.0625;
            }
            const unsigned long long mask = __ballot(valid);
            if (mask) {
                const unsigned mlo = (unsigned)mask, mhi = (unsigned)(mask >> 32);
                const int rank = __builtin_amdgcn_mbcnt_hi(
                                     mhi, __builtin_amdgcn_mbcnt_lo(mlo, 0));
                const int pos = kcur + rank;
                if (valid && pos < 64) cand[wf][pos] = src;  // P(ktot>64) negligible
                kcur += __popcll(mask);
            }
        }

        const int k = kcur < NS ? kcur : NS;       // == unique_cnt
        if (lane == 0) kc[pl] = (unsigned)k;

        int slot = lane;
        if (kcur > NS) {                           // rare: pick 32 smallest idx
            unsigned key = 0x7FFFFFFFu;
            if (lane < kcur && lane < 64) {
                const unsigned qi = __float_as_uint(pts[cand[wf][lane]].w);
                key = (qi << 6) | (unsigned)lane;
            }
            #pragma unroll
            for (int size = 2; size <= 64; size <<= 1) {
                #pragma unroll
                for (int stride = size >> 1; stride > 0; stride >>= 1) {
                    const unsigned partner = (unsigned)__shfl_xor((int)key, stride, 64);
                    const bool keepmin = ((lane & stride) == 0) == ((lane & size) == 0);
                    key = keepmin ? (key < partner ? key : partner)
                                  : (key > partner ? key : partner);
                }
            }
            slot = (int)(key & 63u);
        }
        if (lane < k)
            queue[wf][myqlen + lane] = ((unsigned)pl << 20) | cand[wf][slot];
        myqlen += k;
    }
    if (lane == 0) qlen[wf] = myqlen;
    __syncthreads();

    // ---- MLP: o-split x2, lane-permuted flattened queue, 2-chain FMA ----
    const int q0 = qlen[0], q1 = qlen[1], q2 = qlen[2], q3 = qlen[3];
    const int o1 = q0, o2 = q0 + q1, o3 = o2 + q2;
    const int Qtot = o3 + q3;
    const int Gmax = ((Qtot + 63) >> 6) * 2;       // 64-groups: (s-chunk, half) pairs
    for (int F = tid; F < Gmax * 64; F += 256) {
        const int half = __builtin_amdgcn_readfirstlane((F >> 6) & 1);  // wave-uniform
        const int s = ((F >> 7) << 6) + ((F * 29) & 63);  // lane-permuted sample id
        if (s >= Qtot) continue;
        int w, loc;
        if (s < o1)      { w = 0; loc = s; }
        else if (s < o2) { w = 1; loc = s - o1; }
        else if (s < o3) { w = 2; loc = s - o2; }
        else             { w = 3; loc = s - o3; }
        const unsigned e = queue[w][loc];
        const int pl = (int)(e >> 20);
        const unsigned src = e & 0xFFFFFu;
        const float4 f4 = pts[src];                // L1/L2-hot gather
        const float rx = f4.x - ctr[pl][0];
        const float ry = f4.y - ctr[pl][1];
        const float rz = f4.z - ctr[pl][2];

        float h1[C1];
        #pragma unroll
        for (int c = 0; c < C1; ++c) {             // w1/b1 uniform -> scalar loads
            float a = fmaf(w1[c * 3 + 2], rz,
                      fmaf(w1[c * 3 + 1], ry,
                      fmaf(w1[c * 3 + 0], rx, b1[c])));
            h1[c] = a > 0.f ? a : 0.f;
        }
        const float* w2h = w2 + (half << 10);      // rows [half*32, half*32+32)
        const float* b2h = b2 + (half << 5);
        unsigned* poolrow = &pooled[pl][half << 5];
        #pragma unroll 4
        for (int i = 0; i < 32; ++i) {             // two independent even/odd chains
            float ax = 0.f, ay = 0.f;
            #pragma unroll
            for (int c = 0; c < C1; c += 2) {
                ax = fmaf(w2h[i * 32 + c],     h1[c],     ax);
                ay = fmaf(w2h[i * 32 + c + 1], h1[c + 1], ay);
            }
            float acc = ax + ay + b2h[i];
            acc = acc > 0.f ? acc : 0.f;
            atomicMax(&poolrow[i], __float_as_uint(acc));
        }
    }
    __syncthreads();

    // ---- epilogue: full 65-float rows (density folded in) ----
    for (int u = tid; u < CB * (C2 + 1); u += 256) {
        const int pl = u / (C2 + 1), c = u % (C2 + 1);
        const float v = (c < C2) ? __uint_as_float(pooled[pl][c])
                                 : (float)kc[pl] * (1.0f / (float)C2);
        out[(size_t)(p0 + pl) * (C2 + 1) + c] = v;
    }
}

// ================= fallback: R4 brute-force kernel (ws too small) =================
#define PBLK   16
#define CPW    4
#define BAND   2e-4f

__global__ __launch_bounds__(256, 8) void lse_fallback(
    const float* __restrict__ xyz,
    const float* __restrict__ w1, const float* __restrict__ b1,
    const float* __restrict__ w2, const float* __restrict__ b2,
    float* __restrict__ out)
{
    __shared__ int      lists[PBLK][NS];
    __shared__ int      counts[PBLK];
    __shared__ int      queue[PBLK * NS];
    __shared__ unsigned pooled[PBLK][C2 + 1];
    __shared__ float    ctr[PBLK][3];
    __shared__ float    dens[PBLK];
    __shared__ int      qtotal;

    const int tid = threadIdx.x, lane = tid & 63, wf = tid >> 6;
    const int pt0 = blockIdx.x * PBLK;
    const int bbase = (pt0 >> 12) << 12;

    for (int u = tid; u < PBLK * (C2 + 1); u += 256) ((unsigned*)pooled)[u] = 0u;
    if (tid < PBLK) {
        ctr[tid][0] = xyz[(size_t)(pt0 + tid) * 3 + 0];
        ctr[tid][1] = xyz[(size_t)(pt0 + tid) * 3 + 1];
        ctr[tid][2] = xyz[(size_t)(pt0 + tid) * 3 + 2];
    }
    const int c0 = pt0 + wf * CPW;
    float c2x[CPW], c2y[CPW], c2z[CPW], scc[CPW];
    #pragma unroll
    for (int j = 0; j < CPW; ++j) {
        const int g = __builtin_amdgcn_readfirstlane(c0 + j);
        const float cx = xyz[(size_t)g * 3 + 0];
        const float cy = xyz[(size_t)g * 3 + 1];
        const float cz = xyz[(size_t)g * 3 + 2];
        c2x[j] = -2.0f * cx; c2y[j] = -2.0f * cy; c2z[j] = -2.0f * cz;
        scc[j] = fmaf(cx, cx, fmaf(cy, cy, cz * cz)) - (R2C + BAND);
    }
    int cnt[CPW];
    #pragma unroll
    for (int j = 0; j < CPW; ++j) cnt[j] = 0;

    const float* xb = xyz + (size_t)bbase * 3;
    float qx = xb[lane * 3 + 0], qy = xb[lane * 3 + 1], qz = xb[lane * 3 + 2];
    for (int m0 = 0; m0 < BQ_N; m0 += 64) {
        float nqx = 0.f, nqy = 0.f, nqz = 0.f;
        if (m0 + 64 < BQ_N) {
            const int mn = m0 + 64 + lane;
            nqx = xb[mn * 3 + 0]; nqy = xb[mn * 3 + 1]; nqz = xb[mn * 3 + 2];
        }
        const float nsq = -fmaf(qx, qx, fmaf(qy, qy, qz * qz));
        float t[CPW]; unsigned long long msk[CPW];
        #pragma unroll
        for (int j = 0; j < CPW; ++j) {
            t[j] = fmaf(qx, c2x[j], fmaf(qy, c2y[j], fmaf(qz, c2z[j], scc[j])));
            msk[j] = __ballot(t[j] < nsq);
        }
        if ((msk[0] | msk[1] | msk[2] | msk[3]) != 0ull) {
            #pragma unroll
            for (int j = 0; j < CPW; ++j) {
                unsigned long long mask = msk[j];
                if (mask == 0ull) continue;
                const float u = t[j] - nsq;
                const bool nearb = (mask >> lane) & 1ull;
                const bool strict = u < (-2.0f * BAND);
                bool valid = strict;
                const unsigned long long mS = __ballot(strict);
                if (mS != mask) {
                    if (nearb && !strict) {
                        const double cx = -0.5 * (double)c2x[j];
                        const double cy = -0.5 * (double)c2y[j];
                        const double cz = -0.5 * (double)c2z[j];
                        const double dx = (double)qx - cx;
                        const double dy = (double)qy - cy;
                        const double dz = (double)qz - cz;
                        valid = (dx * dx + dy * dy + dz * dz) < 0.0625;
                    }
                    mask = __ballot(valid);
                    if (mask == 0ull) continue;
                }
                const unsigned mlo = (unsigned)mask, mhi = (unsigned)(mask >> 32);
                const int rank = __builtin_amdgcn_mbcnt_hi(
                                     mhi, __builtin_amdgcn_mbcnt_lo(mlo, 0));
                const int pos = cnt[j] + rank;
                if (valid && pos < NS) lists[wf * CPW + j][pos] = m0 + lane;
                cnt[j] += __popcll(mask);
            }
        }
        qx = nqx; qy = nqy; qz = nqz;
    }
    if (lane == 0) {
        #pragma unroll
        for (int j = 0; j < CPW; ++j) counts[wf * CPW + j] = cnt[j];
    }
    __syncthreads();
    if (tid < PBLK) {
        const int p = tid;
        const int ktot = counts[p];
        const int k = ktot < NS ? ktot : NS;
        dens[p] = (float)k * (1.0f / (float)C2);
        int incl = k;
        #pragma unroll
        for (int d = 1; d < PBLK; d <<= 1) {
            int v = __shfl_up(incl, d, 64);
            if (lane >= d) incl += v;
        }
        const int excl = incl - k;
        if (p == PBLK - 1) qtotal = incl;
        for (int j = 0; j < k; ++j) queue[excl + j] = (p << 12) | lists[p][j];
    }
    __syncthreads();
    const int Q = qtotal;
    for (int j = tid; j < Q; j += 256) {
        const int e = queue[j];
        const int p = e >> 12;
        const int idx = e & (BQ_N - 1);
        const float* nb = xyz + (size_t)(bbase + idx) * 3;
        const float rx = nb[0] - ctr[p][0];
        const float ry = nb[1] - ctr[p][1];
        const float rz = nb[2] - ctr[p][2];
        float h1[C1];
        #pragma unroll
        for (int cc = 0; cc < C1; ++cc) {
            float a = fmaf(w1[cc * 3 + 2], rz,
                      fmaf(w1[cc * 3 + 1], ry,
                      fmaf(w1[cc * 3 + 0], rx, b1[cc])));
            h1[cc] = a > 0.f ? a : 0.f;
        }
        #pragma unroll 2
        for (int o = 0; o < C2; ++o) {
            float acc = b2[o];
            #pragma unroll
            for (int i = 0; i < C1; ++i) acc = fmaf(w2[o * C1 + i], h1[i], acc);
            acc = acc > 0.f ? acc : 0.f;
            atomicMax(&pooled[p][o], __float_as_uint(acc));
        }
    }
    __syncthreads();
    for (int u = tid; u < PBLK * (C2 + 1); u += 256) {
        const int p = u / (C2 + 1);
        const int cc = u % (C2 + 1);
        const float v = (cc < C2) ? __uint_as_float(pooled[p][cc]) : dens[p];
        out[(size_t)(pt0 + p) * (C2 + 1) + cc] = v;
    }
}

extern "C" void kernel_launch(void* const* d_in, const int* in_sizes, int n_in,
                              void* d_out, int out_size, void* d_ws, size_t ws_size,
                              hipStream_t stream) {
    const float* xyz = (const float*)d_in[0];
    const float* w1  = (const float*)d_in[1];
    const float* b1  = (const float*)d_in[2];
    const float* w2  = (const float*)d_in[3];
    const float* b2  = (const float*)d_in[4];
    float* out = (float*)d_out;

    // workspace layout (u32 units):
    // done[4] | counts[NCELLS] | partial[NCELLS] | cellstart[NCELLS+16] |
    // blocksum[256] | blockoff[256] | pcell[NPTS] | ppos[NPTS] | pts[4*NPTS]
    const size_t need = (size_t)(4 + 3 * NCELLS + 16 + 512 + 2 * NPTS + 4 * NPTS) * 4;

    if (ws_size >= need) {
        unsigned* wsu       = (unsigned*)d_ws;
        unsigned* done      = wsu;                      // 4 (only [0] used)
        unsigned* counts    = done + 4;                 // NCELLS
        unsigned* partial   = counts + NCELLS;          // NCELLS
        unsigned* cellstart = partial + NCELLS;         // NCELLS + 16 (sentinel)
        unsigned* blocksum  = cellstart + NCELLS + 16;  // 256
        unsigned* blockoff  = blocksum + 256;           // 256
        unsigned* pcell     = blockoff + 256;           // NPTS
        unsigned* ppos      = pcell + NPTS;             // NPTS
        float4*   pts       = (float4*)(ppos + NPTS);   // NPTS * 4 dwords (16B-aligned)

        hipMemsetAsync(done, 0, (size_t)(4 + NCELLS) * 4, stream);  // done + counts
        grid_count<<<NPTS / 256, 256, 0, stream>>>(xyz, counts, pcell, ppos);
        scan1f<<<NBLK2, SCAN_B, 0, stream>>>(counts, partial, blocksum, blockoff, done);
        grid_scatterF<<<NCELLS / 256, 256, 0, stream>>>(xyz, partial, blockoff,
                                                        pcell, ppos, cellstart, pts);
        lse_grid5<<<NPTS / CB, 256, 0, stream>>>(xyz, cellstart, pts,
                                                 w1, b1, w2, b2, out);
    } else {
        lse_fallback<<<NPTS / PBLK, 256, 0, stream>>>(xyz, w1, b1, w2, b2, out);
    }
}

// Round 14
// 113.386 us; speedup vs baseline: 5.1570x; 1.6722x over previous
//
#include <hip/hip_runtime.h>

// Problem constants (from reference)
#define BQ_B   8
#define BQ_N   4096
#define NS     32
#define C1     32
#define C2     64
#define R2C    0.0625f
#define NPTS   (BQ_B * BQ_N)

// ---- spatial grid ----
#define GD     32                  // cells per dim, cell size 0.25, origin -4 (clamped)
#define NC_B   (GD * GD * GD)      // 32768 cells per batch
#define NCELLS (BQ_B * NC_B)       // 262144 total
#define SCAN_B 1024
#define NBLK2  (NCELLS / SCAN_B)   // 256

__device__ __forceinline__ int cell_coord(float x) {
    int i = (int)floorf((x + 4.0f) * 4.0f);
    return i < 0 ? 0 : (i > GD - 1 ? GD - 1 : i);
}

// ---------- grid build ----------
__global__ __launch_bounds__(256) void grid_count(
    const float* __restrict__ xyz, unsigned* __restrict__ counts,
    unsigned* __restrict__ pcell, unsigned* __restrict__ ppos)
{
    const int i = blockIdx.x * 256 + threadIdx.x;
    const float x = xyz[3 * i], y = xyz[3 * i + 1], z = xyz[3 * i + 2];
    const int ix = cell_coord(x), iy = cell_coord(y), iz = cell_coord(z);
    const unsigned cid = (unsigned)(((i >> 12) * GD + iz) * GD + iy) * GD + ix;
    pcell[i] = cid;
    ppos[i] = atomicAdd(&counts[cid], 1u);
}

// exclusive scan within 1024-blocks; blocksum[b] = block total.
// NOTE: deliberately NOT fused with scan2 via a last-block device fence:
// per-block __threadfence() on gfx950 costs an L2 writeback across XCDs
// (~80 us for 256 blocks, measured R13). Dispatch boundary is free.
__global__ __launch_bounds__(1024) void scan1(
    const unsigned* __restrict__ counts, unsigned* __restrict__ partial,
    unsigned* __restrict__ blocksum)
{
    __shared__ unsigned wsum[16];
    const int tid = threadIdx.x, lane = tid & 63, w = tid >> 6;
    const int g = blockIdx.x * 1024 + tid;
    const unsigned v = counts[g];
    unsigned incl = v;
    #pragma unroll
    for (int d = 1; d < 64; d <<= 1) {
        unsigned t = __shfl_up(incl, d, 64);
        if (lane >= d) incl += t;
    }
    if (lane == 63) wsum[w] = incl;
    __syncthreads();
    if (w == 0 && lane < 16) {
        const unsigned s = wsum[lane];
        unsigned si = s;
        #pragma unroll
        for (int d = 1; d < 16; d <<= 1) {
            unsigned t = __shfl_up(si, d, 64);
            if (lane >= d) si += t;
        }
        wsum[lane] = si - s;                 // exclusive wave offset
        if (lane == 15) blocksum[blockIdx.x] = si;
    }
    __syncthreads();
    partial[g] = wsum[w] + incl - v;         // exclusive within block
}

// exclusive scan of the 256 block sums (single block)
__global__ __launch_bounds__(256) void scan2(
    const unsigned* __restrict__ blocksum, unsigned* __restrict__ blockoff)
{
    __shared__ unsigned ws2[4];
    const int tid = threadIdx.x, lane = tid & 63, w = tid >> 6;
    const unsigned v = blocksum[tid];
    unsigned incl = v;
    #pragma unroll
    for (int d = 1; d < 64; d <<= 1) {
        unsigned t = __shfl_up(incl, d, 64);
        if (lane >= d) incl += t;
    }
    if (lane == 63) ws2[w] = incl;
    __syncthreads();
    unsigned off = 0;
    #pragma unroll
    for (int j = 0; j < 4; ++j) if (j < w) off += ws2[j];
    blockoff[tid] = off + incl - v;
}

// fused: cellstart finalize (all 262144 cells) + point scatter (first NPTS threads)
// Safe fusion: no cross-block data dependency, no fences.
__global__ __launch_bounds__(256) void grid_scatterF(
    const float* __restrict__ xyz,
    const unsigned* __restrict__ partial, const unsigned* __restrict__ blockoff,
    const unsigned* __restrict__ pcell, const unsigned* __restrict__ ppos,
    unsigned* __restrict__ cellstart, float4* __restrict__ pts)
{
    const int g = blockIdx.x * 256 + threadIdx.x;   // 1024 blocks
    cellstart[g] = partial[g] + blockoff[g >> 10];
    if (g == 0) cellstart[NCELLS] = NPTS;
    if (g < NPTS) {
        const unsigned cid = pcell[g];
        const unsigned pos = partial[cid] + blockoff[cid >> 10] + ppos[g];
        float4 v;
        v.x = xyz[3 * g];
        v.y = xyz[3 * g + 1];
        v.z = xyz[3 * g + 2];
        v.w = __uint_as_float((unsigned)(g & (BQ_N - 1)));
        pts[pos] = v;
    }
}

// ---------- main: R9's proven kernel (grid ball-query + o-split atomicMax MLP) ----------
#define CB 8    // centers per block (grid 4096 -> dynamic balance)
#define CW 2    // centers per wave

__global__ __launch_bounds__(256, 8) void lse_grid5(
    const float* __restrict__ xyz,
    const unsigned* __restrict__ cellstart,
    const float4* __restrict__ pts,
    const float* __restrict__ w1, const float* __restrict__ b1,
    const float* __restrict__ w2, const float* __restrict__ b2,
    float* __restrict__ out)
{
    __shared__ unsigned cand[4][64];          // per-wave candidate src positions
    __shared__ unsigned queue[4][CW * NS];    // compact entries: (pl<<20)|src
    __shared__ int      qlen[4];
    __shared__ unsigned pooled[CB][C2 + 1];   // stride 65: bank=(pl+o)%32
    __shared__ float    ctr[CB][3];
    __shared__ unsigned kc[CB];               // k per center (density)

    const int tid  = threadIdx.x, lane = tid & 63, wf = tid >> 6;
    const int p0   = blockIdx.x * CB;         // never straddles a batch
    const int b    = p0 >> 12;

    for (int u = tid; u < CB * (C2 + 1); u += 256) ((unsigned*)pooled)[u] = 0u;

    // hoisted wave-uniform center coords (scalar loads, issued early)
    float scx[CW], scy[CW], scz[CW];
    #pragma unroll
    for (int jc = 0; jc < CW; ++jc) {
        const int g = __builtin_amdgcn_readfirstlane(p0 + wf * CW + jc);
        float x = xyz[3 * g], y = xyz[3 * g + 1], z = xyz[3 * g + 2];
        scx[jc] = __int_as_float(__builtin_amdgcn_readfirstlane(__float_as_int(x)));
        scy[jc] = __int_as_float(__builtin_amdgcn_readfirstlane(__float_as_int(y)));
        scz[jc] = __int_as_float(__builtin_amdgcn_readfirstlane(__float_as_int(z)));
    }
    if (lane == 0) {
        #pragma unroll
        for (int jc = 0; jc < CW; ++jc) {
            ctr[wf * CW + jc][0] = scx[jc];
            ctr[wf * CW + jc][1] = scy[jc];
            ctr[wf * CW + jc][2] = scz[jc];
        }
    }

    int myqlen = 0;
    #pragma unroll
    for (int jc = 0; jc < CW; ++jc) {         // full unroll: s_loads overlap
        const int pl = wf * CW + jc;          // block-local center
        const float cx = scx[jc], cy = scy[jc], cz = scz[jc];
        const int icx = __builtin_amdgcn_readfirstlane(cell_coord(cx));
        const int icy = __builtin_amdgcn_readfirstlane(cell_coord(cy));
        const int icz = __builtin_amdgcn_readfirstlane(cell_coord(cz));
        const int lo = icx > 0 ? icx - 1 : 0;
        const int hi = icx < GD - 1 ? icx + 1 : GD - 1;

        // 9 candidate ranges from wave-uniform scalar loads
        unsigned st[9], cn[9], of[9];
        unsigned T = 0;
        #pragma unroll
        for (int r = 0; r < 9; ++r) {
            const int dz = r / 3 - 1, dy = r % 3 - 1;
            const int rz = icz + dz, ry = icy + dy;
            const bool ok = (rz >= 0) & (rz < GD) & (ry >= 0) & (ry < GD);
            const int rzc = rz < 0 ? 0 : (rz > GD - 1 ? GD - 1 : rz);
            const int ryc = ry < 0 ? 0 : (ry > GD - 1 ? GD - 1 : ry);
            const int cbase = ((b * GD + rzc) * GD + ryc) * GD;
            const unsigned s = cellstart[cbase + lo];
            const unsigned e = cellstart[cbase + hi + 1];
            st[r] = s;
            cn[r] = ok ? e - s : 0u;
            of[r] = T;
            T += cn[r];
        }

        int kcur = 0;
        for (unsigned tb = 0; tb < T; tb += 64) {
            const unsigned t = tb + (unsigned)lane;
            unsigned src = 0;
            #pragma unroll
            for (int r = 0; r < 9; ++r) {          // SGPR operands, pure VALU
                const unsigned d = t - of[r];
                if (d < cn[r]) src = st[r] + d;
            }
            const bool inb = t < T;
            const float4 q4 = pts[src];            // one dwordx4 gather
            const float dx = q4.x - cx, dy = q4.y - cy, dz = q4.z - cz;
            const float d2 = fmaf(dz, dz, fmaf(dy, dy, dx * dx));
            const bool nearb  = inb && (d2 < R2C + 1e-5f);
            const bool strict = inb && (d2 < R2C - 1e-5f);
            bool valid = strict;
            if (nearb && !strict) {                // rare: exact fp64 adjudication
                const double ddx = (double)q4.x - (double)cx;
                const double ddy = (double)q4.y - (double)cy;
                const double ddz = (double)q4.z - (double)cz;
                valid = (ddx * ddx + ddy * ddy + ddz * ddz) < 0.0625;
            }
            const unsigned long long mask = __ballot(valid);
            if (mask) {
                const unsigned mlo = (unsigned)mask, mhi = (unsigned)(mask >> 32);
                const int rank = __builtin_amdgcn_mbcnt_hi(
                                     mhi, __builtin_amdgcn_mbcnt_lo(mlo, 0));
                const int pos = kcur + rank;
                if (valid && pos < 64) cand[wf][pos] = src;  // P(ktot>64) negligible
                kcur += __popcll(mask);
            }
        }

        const int k = kcur < NS ? kcur : NS;       // == unique_cnt
        if (lane == 0) kc[pl] = (unsigned)k;

        int slot = lane;
        if (kcur > NS) {                           // rare: pick 32 smallest idx
            unsigned key = 0x7FFFFFFFu;
            if (lane < kcur && lane < 64) {
                const unsigned qi = __float_as_uint(pts[cand[wf][lane]].w);
                key = (qi << 6) | (unsigned)lane;
            }
            #pragma unroll
            for (int size = 2; size <= 64; size <<= 1) {
                #pragma unroll
                for (int stride = size >> 1; stride > 0; stride >>= 1) {
                    const unsigned partner = (unsigned)__shfl_xor((int)key, stride, 64);
                    const bool keepmin = ((lane & stride) == 0) == ((lane & size) == 0);
                    key = keepmin ? (key < partner ? key : partner)
                                  : (key > partner ? key : partner);
                }
            }
            slot = (int)(key & 63u);
        }
        if (lane < k)
            queue[wf][myqlen + lane] = ((unsigned)pl << 20) | cand[wf][slot];
        myqlen += k;
    }
    if (lane == 0) qlen[wf] = myqlen;
    __syncthreads();

    // ---- MLP: o-split x2, lane-permuted flattened queue, 2-chain FMA ----
    const int q0 = qlen[0], q1 = qlen[1], q2 = qlen[2], q3 = qlen[3];
    const int o1 = q0, o2 = q0 + q1, o3 = o2 + q2;
    const int Qtot = o3 + q3;
    const int Gmax = ((Qtot + 63) >> 6) * 2;       // 64-groups: (s-chunk, half) pairs
    for (int F = tid; F < Gmax * 64; F += 256) {
        const int half = __builtin_amdgcn_readfirstlane((F >> 6) & 1);  // wave-uniform
        const int s = ((F >> 7) << 6) + ((F * 29) & 63);  // lane-permuted sample id
        if (s >= Qtot) continue;
        int w, loc;
        if (s < o1)      { w = 0; loc = s; }
        else if (s < o2) { w = 1; loc = s - o1; }
        else if (s < o3) { w = 2; loc = s - o2; }
        else             { w = 3; loc = s - o3; }
        const unsigned e = queue[w][loc];
        const int pl = (int)(e >> 20);
        const unsigned src = e & 0xFFFFFu;
        const float4 f4 = pts[src];                // L1/L2-hot gather
        const float rx = f4.x - ctr[pl][0];
        const float ry = f4.y - ctr[pl][1];
        const float rz = f4.z - ctr[pl][2];

        float h1[C1];
        #pragma unroll
        for (int c = 0; c < C1; ++c) {             // w1/b1 uniform -> scalar loads
            float a = fmaf(w1[c * 3 + 2], rz,
                      fmaf(w1[c * 3 + 1], ry,
                      fmaf(w1[c * 3 + 0], rx, b1[c])));
            h1[c] = a > 0.f ? a : 0.f;
        }
        const float* w2h = w2 + (half << 10);      // rows [half*32, half*32+32)
        const float* b2h = b2 + (half << 5);
        unsigned* poolrow = &pooled[pl][half << 5];
        #pragma unroll 4
        for (int i = 0; i < 32; ++i) {             // two independent even/odd chains
            float ax = 0.f, ay = 0.f;
            #pragma unroll
            for (int c = 0; c < C1; c += 2) {
                ax = fmaf(w2h[i * 32 + c],     h1[c],     ax);
                ay = fmaf(w2h[i * 32 + c + 1], h1[c + 1], ay);
            }
            float acc = ax + ay + b2h[i];
            acc = acc > 0.f ? acc : 0.f;
            atomicMax(&poolrow[i], __float_as_uint(acc));
        }
    }
    __syncthreads();

    // ---- epilogue: full 65-float rows (density folded in) ----
    for (int u = tid; u < CB * (C2 + 1); u += 256) {
        const int pl = u / (C2 + 1), c = u % (C2 + 1);
        const float v = (c < C2) ? __uint_as_float(pooled[pl][c])
                                 : (float)kc[pl] * (1.0f / (float)C2);
        out[(size_t)(p0 + pl) * (C2 + 1) + c] = v;
    }
}

// ================= fallback: R4 brute-force kernel (ws too small) =================
#define PBLK   16
#define CPW    4
#define BAND   2e-4f

__global__ __launch_bounds__(256, 8) void lse_fallback(
    const float* __restrict__ xyz,
    const float* __restrict__ w1, const float* __restrict__ b1,
    const float* __restrict__ w2, const float* __restrict__ b2,
    float* __restrict__ out)
{
    __shared__ int      lists[PBLK][NS];
    __shared__ int      counts[PBLK];
    __shared__ int      queue[PBLK * NS];
    __shared__ unsigned pooled[PBLK][C2 + 1];
    __shared__ float    ctr[PBLK][3];
    __shared__ float    dens[PBLK];
    __shared__ int      qtotal;

    const int tid = threadIdx.x, lane = tid & 63, wf = tid >> 6;
    const int pt0 = blockIdx.x * PBLK;
    const int bbase = (pt0 >> 12) << 12;

    for (int u = tid; u < PBLK * (C2 + 1); u += 256) ((unsigned*)pooled)[u] = 0u;
    if (tid < PBLK) {
        ctr[tid][0] = xyz[(size_t)(pt0 + tid) * 3 + 0];
        ctr[tid][1] = xyz[(size_t)(pt0 + tid) * 3 + 1];
        ctr[tid][2] = xyz[(size_t)(pt0 + tid) * 3 + 2];
    }
    const int c0 = pt0 + wf * CPW;
    float c2x[CPW], c2y[CPW], c2z[CPW], scc[CPW];
    #pragma unroll
    for (int j = 0; j < CPW; ++j) {
        const int g = __builtin_amdgcn_readfirstlane(c0 + j);
        const float cx = xyz[(size_t)g * 3 + 0];
        const float cy = xyz[(size_t)g * 3 + 1];
        const float cz = xyz[(size_t)g * 3 + 2];
        c2x[j] = -2.0f * cx; c2y[j] = -2.0f * cy; c2z[j] = -2.0f * cz;
        scc[j] = fmaf(cx, cx, fmaf(cy, cy, cz * cz)) - (R2C + BAND);
    }
    int cnt[CPW];
    #pragma unroll
    for (int j = 0; j < CPW; ++j) cnt[j] = 0;

    const float* xb = xyz + (size_t)bbase * 3;
    float qx = xb[lane * 3 + 0], qy = xb[lane * 3 + 1], qz = xb[lane * 3 + 2];
    for (int m0 = 0; m0 < BQ_N; m0 += 64) {
        float nqx = 0.f, nqy = 0.f, nqz = 0.f;
        if (m0 + 64 < BQ_N) {
            const int mn = m0 + 64 + lane;
            nqx = xb[mn * 3 + 0]; nqy = xb[mn * 3 + 1]; nqz = xb[mn * 3 + 2];
        }
        const float nsq = -fmaf(qx, qx, fmaf(qy, qy, qz * qz));
        float t[CPW]; unsigned long long msk[CPW];
        #pragma unroll
        for (int j = 0; j < CPW; ++j) {
            t[j] = fmaf(qx, c2x[j], fmaf(qy, c2y[j], fmaf(qz, c2z[j], scc[j])));
            msk[j] = __ballot(t[j] < nsq);
        }
        if ((msk[0] | msk[1] | msk[2] | msk[3]) != 0ull) {
            #pragma unroll
            for (int j = 0; j < CPW; ++j) {
                unsigned long long mask = msk[j];
                if (mask == 0ull) continue;
                const float u = t[j] - nsq;
                const bool nearb = (mask >> lane) & 1ull;
                const bool strict = u < (-2.0f * BAND);
                bool valid = strict;
                const unsigned long long mS = __ballot(strict);
                if (mS != mask) {
                    if (nearb && !strict) {
                        const double cx = -0.5 * (double)c2x[j];
                        const double cy = -0.5 * (double)c2y[j];
                        const double cz = -0.5 * (double)c2z[j];
                        const double dx = (double)qx - cx;
                        const double dy = (double)qy - cy;
                        const double dz = (double)qz - cz;
                        valid = (dx * dx + dy * dy + dz * dz) < 0.0625;
                    }
                    mask = __ballot(valid);
                    if (mask == 0ull) continue;
                }
                const unsigned mlo = (unsigned)mask, mhi = (unsigned)(mask >> 32);
                const int rank = __builtin_amdgcn_mbcnt_hi(
                                     mhi, __builtin_amdgcn_mbcnt_lo(mlo, 0));
                const int pos = cnt[j] + rank;
                if (valid && pos < NS) lists[wf * CPW + j][pos] = m0 + lane;
                cnt[j] += __popcll(mask);
            }
        }
        qx = nqx; qy = nqy; qz = nqz;
    }
    if (lane == 0) {
        #pragma unroll
        for (int j = 0; j < CPW; ++j) counts[wf * CPW + j] = cnt[j];
    }
    __syncthreads();
    if (tid < PBLK) {
        const int p = tid;
        const int ktot = counts[p];
        const int k = ktot < NS ? ktot : NS;
        dens[p] = (float)k * (1.0f / (float)C2);
        int incl = k;
        #pragma unroll
        for (int d = 1; d < PBLK; d <<= 1) {
            int v = __shfl_up(incl, d, 64);
            if (lane >= d) incl += v;
        }
        const int excl = incl - k;
        if (p == PBLK - 1) qtotal = incl;
        for (int j = 0; j < k; ++j) queue[excl + j] = (p << 12) | lists[p][j];
    }
    __syncthreads();
    const int Q = qtotal;
    for (int j = tid; j < Q; j += 256) {
        const int e = queue[j];
        const int p = e >> 12;
        const int idx = e & (BQ_N - 1);
        const float* nb = xyz + (size_t)(bbase + idx) * 3;
        const float rx = nb[0] - ctr[p][0];
        const float ry = nb[1] - ctr[p][1];
        const float rz = nb[2] - ctr[p][2];
        float h1[C1];
        #pragma unroll
        for (int cc = 0; cc < C1; ++cc) {
            float a = fmaf(w1[cc * 3 + 2], rz,
                      fmaf(w1[cc * 3 + 1], ry,
                      fmaf(w1[cc * 3 + 0], rx, b1[cc])));
            h1[cc] = a > 0.f ? a : 0.f;
        }
        #pragma unroll 2
        for (int o = 0; o < C2; ++o) {
            float acc = b2[o];
            #pragma unroll
            for (int i = 0; i < C1; ++i) acc = fmaf(w2[o * C1 + i], h1[i], acc);
            acc = acc > 0.f ? acc : 0.f;
            atomicMax(&pooled[p][o], __float_as_uint(acc));
        }
    }
    __syncthreads();
    for (int u = tid; u < PBLK * (C2 + 1); u += 256) {
        const int p = u / (C2 + 1);
        const int cc = u % (C2 + 1);
        const float v = (cc < C2) ? __uint_as_float(pooled[p][cc]) : dens[p];
        out[(size_t)(pt0 + p) * (C2 + 1) + cc] = v;
    }
}

extern "C" void kernel_launch(void* const* d_in, const int* in_sizes, int n_in,
                              void* d_out, int out_size, void* d_ws, size_t ws_size,
                              hipStream_t stream) {
    const float* xyz = (const float*)d_in[0];
    const float* w1  = (const float*)d_in[1];
    const float* b1  = (const float*)d_in[2];
    const float* w2  = (const float*)d_in[3];
    const float* b2  = (const float*)d_in[4];
    float* out = (float*)d_out;

    // workspace layout (u32 units):
    // counts[NCELLS] | partial[NCELLS] | cellstart[NCELLS+16] |
    // blocksum[256] | blockoff[256] | pcell[NPTS] | ppos[NPTS] | pts[4*NPTS]
    const size_t need = (size_t)(3 * NCELLS + 16 + 512 + 2 * NPTS + 4 * NPTS) * 4;

    if (ws_size >= need) {
        unsigned* wsu       = (unsigned*)d_ws;
        unsigned* counts    = wsu;                      // NCELLS
        unsigned* partial   = counts + NCELLS;          // NCELLS
        unsigned* cellstart = partial + NCELLS;         // NCELLS + 16 (sentinel)
        unsigned* blocksum  = cellstart + NCELLS + 16;  // 256
        unsigned* blockoff  = blocksum + 256;           // 256
        unsigned* pcell     = blockoff + 256;           // NPTS
        unsigned* ppos      = pcell + NPTS;             // NPTS
        float4*   pts       = (float4*)(ppos + NPTS);   // NPTS * 4 dwords (16B-aligned)

        hipMemsetAsync(counts, 0, (size_t)NCELLS * 4, stream);
        grid_count<<<NPTS / 256, 256, 0, stream>>>(xyz, counts, pcell, ppos);
        scan1<<<NBLK2, SCAN_B, 0, stream>>>(counts, partial, blocksum);
        scan2<<<1, 256, 0, stream>>>(blocksum, blockoff);
        grid_scatterF<<<NCELLS / 256, 256, 0, stream>>>(xyz, partial, blockoff,
                                                        pcell, ppos, cellstart, pts);
        lse_grid5<<<NPTS / CB, 256, 0, stream>>>(xyz, cellstart, pts,
                                                 w1, b1, w2, b2, out);
    } else {
        lse_fallback<<<NPTS / PBLK, 256, 0, stream>>>(xyz, w1, b1, w2, b2, out);
    }
}